// Round 6
// baseline (6480.151 us; speedup 1.0000x reference)
//
#include <hip/hip_runtime.h>
#include <hip/hip_bf16.h>
#include <math.h>

#define NTOK 197

typedef __attribute__((ext_vector_type(8))) short bfx8;
typedef __attribute__((ext_vector_type(4))) float fx4;

#define GLOAD16(gsrc, ldst) __builtin_amdgcn_global_load_lds( \
    (const __attribute__((address_space(1))) void*)(gsrc),    \
    (__attribute__((address_space(3))) void*)(ldst), 16, 0, 0)

__device__ __forceinline__ float gelu_f(float x) {
    return 0.5f * x * (1.0f + erff(x * 0.70710678118654752f));
}

// ---------------------------------------------------------------------------
// Patch extraction + LayerNorm -> bf16. Coalesced float4 loads staged via LDS.
// ---------------------------------------------------------------------------
__global__ __launch_bounds__(256) void patch_ln_k(const float* __restrict__ x,
                                                  __hip_bfloat16* __restrict__ out,
                                                  const float* __restrict__ g,
                                                  const float* __restrict__ bt) {
    const int r = blockIdx.x;          // 0..12543
    const int t = threadIdx.x;
    const int b = r / 196, p = r % 196;
    const int ph = p / 14, pw = p % 14;

    __shared__ float px[768];
    if (t < 192) {
        int rr = t >> 2, seg = t & 3;
        int c = rr >> 4, h1 = rr & 15;
        const float* src = x + (((size_t)b * 3 + c) * 224 + (ph * 16 + h1)) * 224
                             + pw * 16 + seg * 4;
        float4 v4 = *(const float4*)src;
        px[(h1 * 16 + seg * 4 + 0) * 3 + c] = v4.x;
        px[(h1 * 16 + seg * 4 + 1) * 3 + c] = v4.y;
        px[(h1 * 16 + seg * 4 + 2) * 3 + c] = v4.z;
        px[(h1 * 16 + seg * 4 + 3) * 3 + c] = v4.w;
    }
    __syncthreads();

    float v[3];
    #pragma unroll
    for (int i = 0; i < 3; ++i) v[i] = px[t + i * 256];
    float s = v[0] + v[1] + v[2];
    float sq = v[0]*v[0] + v[1]*v[1] + v[2]*v[2];
    #pragma unroll
    for (int off = 32; off; off >>= 1) { s += __shfl_xor(s, off); sq += __shfl_xor(sq, off); }
    __shared__ float ss[4], s2[4];
    const int w = t >> 6;
    if ((t & 63) == 0) { ss[w] = s; s2[w] = sq; }
    __syncthreads();
    s  = ss[0] + ss[1] + ss[2] + ss[3];
    sq = s2[0] + s2[1] + s2[2] + s2[3];
    const float inv = 1.0f / 768.0f;
    float mu = s * inv;
    float var = sq * inv - mu * mu;
    float rstd = rsqrtf(var + 1e-5f);
    __hip_bfloat16* o = out + (size_t)r * 768;
    #pragma unroll
    for (int i = 0; i < 3; ++i) {
        int d = t + i * 256;
        o[d] = (__hip_bfloat16)((v[i] - mu) * rstd * g[d] + bt[d]);
    }
}

// ---------------------------------------------------------------------------
// Row LayerNorm over 768 fp32 -> OT
// ---------------------------------------------------------------------------
template <typename OT>
__global__ __launch_bounds__(256) void ln_k(const float* __restrict__ in,
                                            OT* __restrict__ out,
                                            const float* __restrict__ g,
                                            const float* __restrict__ bt) {
    const int r = blockIdx.x;
    const int t = threadIdx.x;
    const float* xr = in + (size_t)r * 768;
    float v0 = xr[t], v1 = xr[t + 256], v2 = xr[t + 512];
    float s = v0 + v1 + v2;
    float sq = v0*v0 + v1*v1 + v2*v2;
    #pragma unroll
    for (int off = 32; off; off >>= 1) { s += __shfl_xor(s, off); sq += __shfl_xor(sq, off); }
    __shared__ float ss[4], s2[4];
    const int w = t >> 6;
    if ((t & 63) == 0) { ss[w] = s; s2[w] = sq; }
    __syncthreads();
    s  = ss[0] + ss[1] + ss[2] + ss[3];
    sq = s2[0] + s2[1] + s2[2] + s2[3];
    const float inv = 1.0f / 768.0f;
    float mu = s * inv;
    float var = sq * inv - mu * mu;
    float rstd = rsqrtf(var + 1e-5f);
    OT* o = out + (size_t)r * 768;
    o[t]       = (OT)((v0 - mu) * rstd * g[t]       + bt[t]);
    o[t + 256] = (OT)((v1 - mu) * rstd * g[t + 256] + bt[t + 256]);
    o[t + 512] = (OT)((v2 - mu) * rstd * g[t + 512] + bt[t + 512]);
}

// ---------------------------------------------------------------------------
// LN of CLS rows only -> bf16 [128][768] (rows 64..127 zeroed)
// ---------------------------------------------------------------------------
__global__ __launch_bounds__(256) void ln_cls_k(const float* __restrict__ in,
                                                __hip_bfloat16* __restrict__ out,
                                                const float* __restrict__ g,
                                                const float* __restrict__ bt) {
    const int b = blockIdx.x;   // 0..127
    const int t = threadIdx.x;
    if (b >= 64) {
        #pragma unroll
        for (int i = 0; i < 3; ++i) out[(size_t)b * 768 + t + i * 256] = (__hip_bfloat16)0.0f;
        return;
    }
    const float* xr = in + (size_t)b * 197 * 768;
    float v0 = xr[t], v1 = xr[t + 256], v2 = xr[t + 512];
    float s = v0 + v1 + v2;
    float sq = v0*v0 + v1*v1 + v2*v2;
    #pragma unroll
    for (int off = 32; off; off >>= 1) { s += __shfl_xor(s, off); sq += __shfl_xor(sq, off); }
    __shared__ float ss[4], s2[4];
    const int w = t >> 6;
    if ((t & 63) == 0) { ss[w] = s; s2[w] = sq; }
    __syncthreads();
    s  = ss[0] + ss[1] + ss[2] + ss[3];
    sq = s2[0] + s2[1] + s2[2] + s2[3];
    const float inv = 1.0f / 768.0f;
    float mu = s * inv;
    float var = sq * inv - mu * mu;
    float rstd = rsqrtf(var + 1e-5f);
    __hip_bfloat16* o = out + (size_t)b * 768;
    o[t]       = (__hip_bfloat16)((v0 - mu) * rstd * g[t]       + bt[t]);
    o[t + 256] = (__hip_bfloat16)((v1 - mu) * rstd * g[t + 256] + bt[t + 256]);
    o[t + 512] = (__hip_bfloat16)((v2 - mu) * rstd * g[t + 512] + bt[t + 512]);
}

// ---------------------------------------------------------------------------
// z = concat(cls, p_ln) + pos  -> [64,197,768] fp32
// ---------------------------------------------------------------------------
__global__ __launch_bounds__(256) void build_z_k(const float* __restrict__ pln,
                                                 const float* __restrict__ cls,
                                                 const float* __restrict__ pos,
                                                 float* __restrict__ z) {
    size_t idx = (size_t)blockIdx.x * 256 + threadIdx.x;
    int d  = idx % 768;
    size_t tkb = idx / 768;
    int tk = tkb % 197;
    int b  = tkb / 197;
    float v = (tk == 0) ? cls[d] : pln[((size_t)b * 196 + (tk - 1)) * 768 + d];
    z[idx] = v + pos[(size_t)tk * 768 + d];
}

// ---------------------------------------------------------------------------
// Weight convert + transpose: fp32 [K,N] -> bf16 [N,K], z-strided output
// ---------------------------------------------------------------------------
__global__ __launch_bounds__(256) void wconv_k(const float* __restrict__ W,
                                               __hip_bfloat16* __restrict__ Wt,
                                               int K, int N, size_t ostride) {
    __shared__ float tl[64][65];
    const int t = threadIdx.x;
    const int n0 = blockIdx.x * 64, k0 = blockIdx.y * 64;
    const size_t ibase = (size_t)blockIdx.z * K * N;
    const size_t obase = (size_t)blockIdx.z * ostride;
    #pragma unroll
    for (int i = 0; i < 16; ++i) {
        int idx = i * 256 + t;
        int kl = idx >> 6, nl = idx & 63;
        tl[kl][nl] = W[ibase + (size_t)(k0 + kl) * N + n0 + nl];
    }
    __syncthreads();
    #pragma unroll
    for (int i = 0; i < 16; ++i) {
        int idx = i * 256 + t;
        int nl = idx >> 6, kl = idx & 63;
        Wt[obase + (size_t)(n0 + nl) * K + k0 + kl] = (__hip_bfloat16)tl[kl][nl];
    }
}

// ---------------------------------------------------------------------------
// W_head transpose: fp32 [768][1000] -> bf16 [1024][768], pad rows zeroed
// ---------------------------------------------------------------------------
__global__ __launch_bounds__(256) void whT_k(const float* __restrict__ W,
                                             __hip_bfloat16* __restrict__ Wt) {
    __shared__ float tl[64][65];
    const int t = threadIdx.x;
    const int n0 = blockIdx.x * 64, k0 = blockIdx.y * 64;
    #pragma unroll
    for (int i = 0; i < 16; ++i) {
        int idx = i * 256 + t;
        int kl = idx >> 6, nl = idx & 63;
        int n = n0 + nl;
        tl[kl][nl] = (n < 1000) ? W[(size_t)(k0 + kl) * 1000 + n] : 0.f;
    }
    __syncthreads();
    #pragma unroll
    for (int i = 0; i < 16; ++i) {
        int idx = i * 256 + t;
        int nl = idx >> 6, kl = idx & 63;
        Wt[(size_t)(n0 + nl) * 768 + k0 + kl] = (__hip_bfloat16)tl[kl][nl];
    }
}

// ---------------------------------------------------------------------------
// 128x128 bf16 MFMA GEMM, BK=64 (kept for the small head GEMM)
// ---------------------------------------------------------------------------
template <int EPI, typename OT>
__global__ __launch_bounds__(256) void mgemm_k(const __hip_bfloat16* __restrict__ A,
                                               const __hip_bfloat16* __restrict__ Wt,
                                               const float* __restrict__ bias,
                                               const float* __restrict__ resid,
                                               OT* __restrict__ C,
                                               int M, int N, int K) {
    __shared__ __align__(16) char sA[16384];
    __shared__ __align__(16) char sB[16384];
    const int t = threadIdx.x;
    const int lane = t & 63, w = t >> 6;
    const int wr = w >> 1, wc = w & 1;
    const int lrow = lane & 15, lgr = lane >> 4;
    const int bm = blockIdx.y * 128, bn = blockIdx.x * 128;

    const __hip_bfloat16* aSrc[4];
    const __hip_bfloat16* bSrc[4];
    #pragma unroll
    for (int i = 0; i < 4; ++i) {
        int q = t + i * 256;          // 0..1023
        int r = q >> 3, c = q & 7;
        int gc = c ^ (r & 7);
        aSrc[i] = A  + (size_t)(bm + r) * K + gc * 8;
        bSrc[i] = Wt + (size_t)(bn + r) * K + gc * 8;
    }

    int aoff[4][2], boff[4][2];
    #pragma unroll
    for (int m = 0; m < 4; ++m) {
        int ra = wr * 64 + m * 16 + lrow;
        int rb = wc * 64 + m * 16 + lrow;
        #pragma unroll
        for (int ks = 0; ks < 2; ++ks) {
            aoff[m][ks] = ra * 128 + (((ks * 4 + lgr) ^ (ra & 7)) << 4);
            boff[m][ks] = rb * 128 + (((ks * 4 + lgr) ^ (rb & 7)) << 4);
        }
    }

    fx4 acc[4][4];
    #pragma unroll
    for (int m = 0; m < 4; ++m)
        #pragma unroll
        for (int n = 0; n < 4; ++n)
            #pragma unroll
            for (int e = 0; e < 4; ++e) acc[m][n][e] = 0.f;

    for (int k0 = 0; k0 < K; k0 += 64) {
        #pragma unroll
        for (int i = 0; i < 4; ++i) GLOAD16(aSrc[i] + k0, sA + (t + i * 256) * 16);
        #pragma unroll
        for (int i = 0; i < 4; ++i) GLOAD16(bSrc[i] + k0, sB + (t + i * 256) * 16);
        __syncthreads();
        #pragma unroll
        for (int ks = 0; ks < 2; ++ks) {
            bfx8 av[4], bv[4];
            #pragma unroll
            for (int m = 0; m < 4; ++m) {
                av[m] = *(const bfx8*)(sA + aoff[m][ks]);
                bv[m] = *(const bfx8*)(sB + boff[m][ks]);
            }
            #pragma unroll
            for (int m = 0; m < 4; ++m)
                #pragma unroll
                for (int n = 0; n < 4; ++n)
                    acc[m][n] = __builtin_amdgcn_mfma_f32_16x16x32_bf16(av[m], bv[n], acc[m][n], 0, 0, 0);
        }
        __syncthreads();
    }

    #pragma unroll
    for (int m = 0; m < 4; ++m) {
        #pragma unroll
        for (int n = 0; n < 4; ++n) {
            const int col = bn + wc * 64 + n * 16 + lrow;
            float bv2 = (EPI >= 1) ? bias[col] : 0.f;
            #pragma unroll
            for (int e = 0; e < 4; ++e) {
                const int row = bm + wr * 64 + m * 16 + lgr * 4 + e;
                if (row < M) {
                    float v = acc[m][n][e] + bv2;
                    if (EPI == 2) v = gelu_f(v);
                    if (EPI == 3) v += resid[(size_t)row * N + col];
                    C[(size_t)row * N + col] = (OT)v;
                }
            }
        }
    }
}

// ---------------------------------------------------------------------------
// 256x256 bf16 MFMA GEMM, 8 waves (2x4), BK=64, double-buffered 2-phase:
// issue STAGE(next) before compute(cur); one barrier per K-step (drains vmcnt).
// LDS 128 KiB -> 1 block/CU. Same XOR-chunk swizzle (slot = chunk ^ (row&7)).
// A must have ceil(M/256)*256 readable rows. N%256==0, K%64==0.
// ---------------------------------------------------------------------------
template <int EPI, typename OT>
__global__ __launch_bounds__(512, 2) void mgemm256_k(const __hip_bfloat16* __restrict__ A,
                                                     const __hip_bfloat16* __restrict__ Wt,
                                                     const float* __restrict__ bias,
                                                     const float* __restrict__ resid,
                                                     OT* __restrict__ C,
                                                     int M, int N, int K) {
    __shared__ __align__(16) char sA[2][32768];
    __shared__ __align__(16) char sB[2][32768];
    const int t = threadIdx.x;            // 0..511
    const int lane = t & 63, w = t >> 6;  // 8 waves
    const int wr = w >> 2, wc = w & 3;    // 2 x 4 -> 128x64 per wave
    const int lrow = lane & 15, lgr = lane >> 4;
    const int bm = blockIdx.y * 256, bn = blockIdx.x * 256;

    const __hip_bfloat16* aSrc[4];
    const __hip_bfloat16* bSrc[4];
    #pragma unroll
    for (int i = 0; i < 4; ++i) {
        int q = t + i * 512;              // 0..2047
        int r = q >> 3, c = q & 7;
        int gc = c ^ (r & 7);
        aSrc[i] = A  + (size_t)(bm + r) * K + gc * 8;
        bSrc[i] = Wt + (size_t)(bn + r) * K + gc * 8;
    }

    int aoff[8][2], boff[4][2];
    #pragma unroll
    for (int m = 0; m < 8; ++m) {
        int ra = wr * 128 + m * 16 + lrow;
        #pragma unroll
        for (int ks = 0; ks < 2; ++ks)
            aoff[m][ks] = ra * 128 + (((ks * 4 + lgr) ^ (ra & 7)) << 4);
    }
    #pragma unroll
    for (int n = 0; n < 4; ++n) {
        int rb = wc * 64 + n * 16 + lrow;
        #pragma unroll
        for (int ks = 0; ks < 2; ++ks)
            boff[n][ks] = rb * 128 + (((ks * 4 + lgr) ^ (rb & 7)) << 4);
    }

    fx4 acc[8][4];
    #pragma unroll
    for (int m = 0; m < 8; ++m)
        #pragma unroll
        for (int n = 0; n < 4; ++n)
            #pragma unroll
            for (int e = 0; e < 4; ++e) acc[m][n][e] = 0.f;

    const int NK = K >> 6;

    // prologue: stage k-tile 0 into buf 0
    #pragma unroll
    for (int i = 0; i < 4; ++i) GLOAD16(aSrc[i], sA[0] + (t + i * 512) * 16);
    #pragma unroll
    for (int i = 0; i < 4; ++i) GLOAD16(bSrc[i], sB[0] + (t + i * 512) * 16);
    __syncthreads();

    int cur = 0;
    for (int kt = 1; kt < NK; ++kt) {
        const int nxt = cur ^ 1;
        // issue next-tile staging first (overlaps with compute below)
        #pragma unroll
        for (int i = 0; i < 4; ++i) GLOAD16(aSrc[i] + kt * 64, sA[nxt] + (t + i * 512) * 16);
        #pragma unroll
        for (int i = 0; i < 4; ++i) GLOAD16(bSrc[i] + kt * 64, sB[nxt] + (t + i * 512) * 16);
        // compute on current buffer
        const char* bA = sA[cur];
        const char* bB = sB[cur];
        #pragma unroll
        for (int ks = 0; ks < 2; ++ks) {
            bfx8 av[8], bv[4];
            #pragma unroll
            for (int m = 0; m < 8; ++m) av[m] = *(const bfx8*)(bA + aoff[m][ks]);
            #pragma unroll
            for (int n = 0; n < 4; ++n) bv[n] = *(const bfx8*)(bB + boff[n][ks]);
            #pragma unroll
            for (int m = 0; m < 8; ++m)
                #pragma unroll
                for (int n = 0; n < 4; ++n)
                    acc[m][n] = __builtin_amdgcn_mfma_f32_16x16x32_bf16(av[m], bv[n], acc[m][n], 0, 0, 0);
        }
        __syncthreads();   // drains vmcnt(0): next buffer ready
        cur = nxt;
    }
    // final k-tile compute (no prefetch)
    {
        const char* bA = sA[cur];
        const char* bB = sB[cur];
        #pragma unroll
        for (int ks = 0; ks < 2; ++ks) {
            bfx8 av[8], bv[4];
            #pragma unroll
            for (int m = 0; m < 8; ++m) av[m] = *(const bfx8*)(bA + aoff[m][ks]);
            #pragma unroll
            for (int n = 0; n < 4; ++n) bv[n] = *(const bfx8*)(bB + boff[n][ks]);
            #pragma unroll
            for (int m = 0; m < 8; ++m)
                #pragma unroll
                for (int n = 0; n < 4; ++n)
                    acc[m][n] = __builtin_amdgcn_mfma_f32_16x16x32_bf16(av[m], bv[n], acc[m][n], 0, 0, 0);
        }
    }

    #pragma unroll
    for (int m = 0; m < 8; ++m) {
        #pragma unroll
        for (int n = 0; n < 4; ++n) {
            const int col = bn + wc * 64 + n * 16 + lrow;
            float bv2 = (EPI >= 1) ? bias[col] : 0.f;
            #pragma unroll
            for (int e = 0; e < 4; ++e) {
                const int row = bm + wr * 128 + m * 16 + lgr * 4 + e;
                if (row < M) {
                    float v = acc[m][n][e] + bv2;
                    if (EPI == 2) v = gelu_f(v);
                    if (EPI == 3) v += resid[(size_t)row * N + col];
                    C[(size_t)row * N + col] = (OT)v;
                }
            }
        }
    }
}

// ---------------------------------------------------------------------------
// MFMA fused attention on fused QKV buffer (row stride 2304).
// ---------------------------------------------------------------------------
__global__ __launch_bounds__(256) void attn_k(const __hip_bfloat16* __restrict__ QKV,
                                              __hip_bfloat16* __restrict__ O) {
    __shared__ __align__(16) char Ks[224 * 128];   // 28672
    __shared__ __align__(16) char VTs[64 * 464];   // 29696
    __shared__ __align__(16) char Ps[4][7424];     // 4 x (16 rows x 464B)

    const int h = blockIdx.x;
    const int b = blockIdx.y;
    const int t = threadIdx.x;
    const int lane = t & 63, w = t >> 6;
    const int rho = lane & 15, g = lane >> 4;
    const size_t base = (size_t)b * NTOK * 2304;
    const int qoff = h * 64, koff = 768 + h * 64, voff = 1536 + h * 64;
    const size_t obase = ((size_t)b * NTOK) * 768 + h * 64;

    #pragma unroll
    for (int i = 0; i < 7; ++i) {
        int q = t + i * 256;            // 0..1791
        int j = q >> 3, c = q & 7;
        int gc = c ^ (j & 7);
        GLOAD16(QKV + base + (size_t)j * 2304 + koff + gc * 8, Ks + q * 16);
    }
    #pragma unroll
    for (int i = 0; i < 7; ++i) {
        int q = t + i * 256;
        int tok = q >> 3, c = q & 7;
        bfx8 vv = {0, 0, 0, 0, 0, 0, 0, 0};
        if (tok < NTOK) vv = *(const bfx8*)(QKV + base + (size_t)tok * 2304 + voff + c * 8);
        #pragma unroll
        for (int u = 0; u < 8; ++u)
            *(unsigned short*)(VTs + (c * 8 + u) * 464 + tok * 2) = (unsigned short)vv[u];
    }
    __syncthreads();

    char* Pw = Ps[w];

    for (int qt = w; qt < 13; qt += 4) {
        const int q0 = qt * 16;
        fx4 s[13];
        #pragma unroll
        for (int nt = 0; nt < 13; ++nt)
            #pragma unroll
            for (int e = 0; e < 4; ++e) s[nt][e] = 0.f;
        #pragma unroll
        for (int ks = 0; ks < 2; ++ks) {
            bfx8 av = *(const bfx8*)(QKV + base + (size_t)(q0 + rho) * 2304 + qoff + ks * 32 + g * 8);
            #pragma unroll
            for (int nt = 0; nt < 13; ++nt) {
                int r = nt * 16 + rho;
                bfx8 bv = *(const bfx8*)(Ks + r * 128 + (((ks * 4 + g) ^ (r & 7)) << 4));
                s[nt] = __builtin_amdgcn_mfma_f32_16x16x32_bf16(av, bv, s[nt], 0, 0, 0);
            }
        }
        float mx[4] = {-1e30f, -1e30f, -1e30f, -1e30f};
        #pragma unroll
        for (int nt = 0; nt < 13; ++nt) {
            #pragma unroll
            for (int e = 0; e < 4; ++e) {
                float v = s[nt][e] * 0.125f;
                if (nt == 12 && rho >= 5) v = -1e30f;
                s[nt][e] = v;
                mx[e] = fmaxf(mx[e], v);
            }
        }
        #pragma unroll
        for (int off = 1; off < 16; off <<= 1)
            #pragma unroll
            for (int e = 0; e < 4; ++e) mx[e] = fmaxf(mx[e], __shfl_xor(mx[e], off));
        float sm[4] = {0.f, 0.f, 0.f, 0.f};
        #pragma unroll
        for (int nt = 0; nt < 13; ++nt)
            #pragma unroll
            for (int e = 0; e < 4; ++e) {
                float p = __expf(s[nt][e] - mx[e]);
                s[nt][e] = p;
                sm[e] += p;
            }
        #pragma unroll
        for (int off = 1; off < 16; off <<= 1)
            #pragma unroll
            for (int e = 0; e < 4; ++e) sm[e] += __shfl_xor(sm[e], off);
        float inv[4];
        #pragma unroll
        for (int e = 0; e < 4; ++e) inv[e] = 1.0f / sm[e];

        #pragma unroll
        for (int nt = 0; nt < 13; ++nt)
            #pragma unroll
            for (int e = 0; e < 4; ++e) {
                int row = g * 4 + e;
                int col = nt * 16 + rho;
                *(__hip_bfloat16*)(Pw + row * 464 + col * 2) =
                    (__hip_bfloat16)(s[nt][e] * inv[e]);
            }
        #pragma unroll
        for (int e = 0; e < 4; ++e)
            *(__hip_bfloat16*)(Pw + (g * 4 + e) * 464 + (208 + rho) * 2) = (__hip_bfloat16)0.0f;

        __builtin_amdgcn_sched_barrier(0);
        asm volatile("s_waitcnt lgkmcnt(0)" ::: "memory");
        __builtin_amdgcn_sched_barrier(0);

        #pragma unroll
        for (int dt = 0; dt < 4; ++dt) {
            fx4 o;
            #pragma unroll
            for (int e = 0; e < 4; ++e) o[e] = 0.f;
            #pragma unroll
            for (int ks = 0; ks < 7; ++ks) {
                bfx8 pa = *(const bfx8*)(Pw + rho * 464 + (ks * 4 + g) * 16);
                bfx8 bv = *(const bfx8*)(VTs + (dt * 16 + rho) * 464 + (ks * 4 + g) * 16);
                o = __builtin_amdgcn_mfma_f32_16x16x32_bf16(pa, bv, o, 0, 0, 0);
            }
            #pragma unroll
            for (int e = 0; e < 4; ++e) {
                int qrow = q0 + g * 4 + e;
                if (qrow < NTOK)
                    O[obase + (size_t)qrow * 768 + dt * 16 + rho] = (__hip_bfloat16)o[e];
            }
        }
    }
}

// ---------------------------------------------------------------------------
// Head softmax: out[b,:] = softmax(logits[b,:1000] + b_head)
// ---------------------------------------------------------------------------
__global__ __launch_bounds__(256) void shead_k(const float* __restrict__ logits,
                                               const float* __restrict__ bh,
                                               float* __restrict__ out) {
    const int b = blockIdx.x;
    const int t = threadIdx.x;
    __shared__ float lg[1000];
    __shared__ float red[4];

    for (int c = t; c < 1000; c += 256) lg[c] = logits[(size_t)b * 1024 + c] + bh[c];
    __syncthreads();

    float m = -1e30f;
    for (int c = t; c < 1000; c += 256) m = fmaxf(m, lg[c]);
    #pragma unroll
    for (int off = 32; off; off >>= 1) m = fmaxf(m, __shfl_xor(m, off));
    if ((t & 63) == 0) red[t >> 6] = m;
    __syncthreads();
    m = fmaxf(fmaxf(red[0], red[1]), fmaxf(red[2], red[3]));
    __syncthreads();

    float sum = 0.f;
    for (int c = t; c < 1000; c += 256) sum += __expf(lg[c] - m);
    #pragma unroll
    for (int off = 32; off; off >>= 1) sum += __shfl_xor(sum, off);
    if ((t & 63) == 0) red[t >> 6] = sum;
    __syncthreads();
    sum = red[0] + red[1] + red[2] + red[3];
    const float invs = 1.0f / sum;
    for (int c = t; c < 1000; c += 256) out[(size_t)b * 1000 + c] = __expf(lg[c] - m) * invs;
}

// ---------------------------------------------------------------------------
// Driver
// ---------------------------------------------------------------------------
extern "C" void kernel_launch(void* const* d_in, const int* in_sizes, int n_in,
                              void* d_out, int out_size, void* d_ws, size_t ws_size,
                              hipStream_t stream) {
    const float* x        = (const float*)d_in[0];
    const float* ln_p_g   = (const float*)d_in[1];
    const float* ln_p_b   = (const float*)d_in[2];
    const float* W_patch  = (const float*)d_in[3];
    const float* b_patch  = (const float*)d_in[4];
    const float* ln_e_g   = (const float*)d_in[5];
    const float* ln_e_b   = (const float*)d_in[6];
    const float* pos_emb  = (const float*)d_in[7];
    const float* cls_tok  = (const float*)d_in[8];
    const float* ln_a_g   = (const float*)d_in[9];
    const float* ln_a_b   = (const float*)d_in[10];
    const float* Wq       = (const float*)d_in[11];
    const float* Wk       = (const float*)d_in[12];
    const float* Wv       = (const float*)d_in[13];
    const float* Wo       = (const float*)d_in[14];
    const float* bo       = (const float*)d_in[15];
    const float* ln_f_g   = (const float*)d_in[16];
    const float* ln_f_b   = (const float*)d_in[17];
    const float* W1       = (const float*)d_in[18];
    const float* b1       = (const float*)d_in[19];
    const float* W2       = (const float*)d_in[20];
    const float* b2       = (const float*)d_in[21];
    const float* ln_out_g = (const float*)d_in[22];
    const float* ln_out_b = (const float*)d_in[23];
    const float* W_head   = (const float*)d_in[24];
    const float* b_head   = (const float*)d_in[25];

    typedef __hip_bfloat16 bf;
    const int M  = 12608;               // 64*197
    const int MP = 12800;               // padded to 50*256
    char* p = (char*)d_ws;

    float* Z   = (float*)p;            p += (size_t)MP * 768 * 4;      // fp32 residual
    bf* XA     = (bf*)p;               p += (size_t)MP * 768 * 2;      // LN out (bf16)
    bf* QKV    = (bf*)p;               p += (size_t)MP * 2304 * 2;     // fused q,k,v
    bf* OB     = (bf*)p;               p += (size_t)MP * 768 * 2;
    char* FFHc = p;                    p += (size_t)MP * 3072 * 2;     // bf16 GELU buf
    bf* FFH    = (bf*)FFHc;
    float* PE  = (float*)FFHc;                                          // alias: patch-embed fp32
    float* E2  = (float*)(FFHc + (size_t)MP * 768 * 4);                 // alias: ln_e out fp32
    bf* WQKVT  = (bf*)p;               p += (size_t)12 * 2304 * 768 * 2;
    bf* WoT    = (bf*)p;               p += (size_t)12 * 768 * 768 * 2;
    bf* W1T    = (bf*)p;               p += (size_t)12 * 3072 * 768 * 2;
    bf* W2T    = (bf*)p;               p += (size_t)12 * 768 * 3072 * 2;
    bf* WpT    = (bf*)p;               p += (size_t)768 * 768 * 2;
    bf* WhT    = (bf*)p;               p += (size_t)1024 * 768 * 2;
    bf* CLS    = (bf*)p;               p += (size_t)128 * 768 * 2;
    float* LOG = (float*)p;            p += (size_t)64 * 1024 * 4;

    const size_t QKVS = (size_t)2304 * 768;

    // weight convert + transpose (every launch)
    wconv_k<<<dim3(12, 12, 12), 256, 0, stream>>>(Wq, WQKVT,             768, 768,  QKVS);
    wconv_k<<<dim3(12, 12, 12), 256, 0, stream>>>(Wk, WQKVT + 768 * 768, 768, 768,  QKVS);
    wconv_k<<<dim3(12, 12, 12), 256, 0, stream>>>(Wv, WQKVT + 1536 * 768,768, 768,  QKVS);
    wconv_k<<<dim3(12, 12, 12), 256, 0, stream>>>(Wo, WoT,  768, 768,  (size_t)768 * 768);
    wconv_k<<<dim3(48, 12, 12), 256, 0, stream>>>(W1, W1T,  768, 3072, (size_t)3072 * 768);
    wconv_k<<<dim3(12, 48, 12), 256, 0, stream>>>(W2, W2T,  3072, 768, (size_t)768 * 3072);
    wconv_k<<<dim3(12, 12, 1),  256, 0, stream>>>(W_patch, WpT, 768, 768, 0);
    whT_k  <<<dim3(16, 12),     256, 0, stream>>>(W_head, WhT);

    // patch embed pipeline (12544 = 49*256 exactly)
    patch_ln_k<<<12544, 256, 0, stream>>>(x, XA, ln_p_g, ln_p_b);
    mgemm256_k<1, float><<<dim3(3, 49), 512, 0, stream>>>(XA, WpT, b_patch, nullptr, PE, 12544, 768, 768);
    ln_k<float><<<12544, 256, 0, stream>>>(PE, E2, ln_e_g, ln_e_b);
    build_z_k<<<37824, 256, 0, stream>>>(E2, cls_tok, pos_emb, Z);

    for (int i = 0; i < 12; ++i) {
        bf* WQKVT_i = WQKVT + (size_t)i * QKVS;
        bf* WoT_i   = WoT + (size_t)i * 768 * 768;
        bf* W1T_i   = W1T + (size_t)i * 3072 * 768;
        bf* W2T_i   = W2T + (size_t)i * 768 * 3072;

        ln_k<bf><<<M, 256, 0, stream>>>(Z, XA, ln_a_g + (size_t)i * 768, ln_a_b + (size_t)i * 768);
        mgemm256_k<0, bf><<<dim3(9, 50), 512, 0, stream>>>(XA, WQKVT_i, nullptr, nullptr, QKV, M, 2304, 768);
        attn_k<<<dim3(12, 64), 256, 0, stream>>>(QKV, OB);
        mgemm256_k<3, float><<<dim3(3, 50), 512, 0, stream>>>(OB, WoT_i, bo + (size_t)i * 768, Z, Z, M, 768, 768);
        ln_k<bf><<<M, 256, 0, stream>>>(Z, XA, ln_f_g + (size_t)i * 768, ln_f_b + (size_t)i * 768);
        mgemm256_k<2, bf><<<dim3(12, 50), 512, 0, stream>>>(XA, W1T_i, b1 + (size_t)i * 3072, nullptr, FFH, M, 3072, 768);
        mgemm256_k<3, float><<<dim3(3, 50), 512, 0, stream>>>(FFH, W2T_i, b2 + (size_t)i * 768, Z, Z, M, 768, 3072);
    }

    // head: LN(CLS rows) -> logits GEMM (128^2 kernel) -> softmax
    ln_cls_k<<<128, 256, 0, stream>>>(Z, CLS, ln_out_g, ln_out_b);
    mgemm_k<0, float><<<dim3(8, 1), 256, 0, stream>>>(CLS, WhT, nullptr, nullptr, LOG, 64, 1024, 768);
    shead_k<<<64, 256, 0, stream>>>(LOG, b_head, (float*)d_out);
}

// Round 7
// 6238.849 us; speedup vs baseline: 1.0387x; 1.0387x over previous
//
#include <hip/hip_runtime.h>
#include <hip/hip_bf16.h>
#include <math.h>

#define NTOK 197

typedef __attribute__((ext_vector_type(8))) short bfx8;
typedef __attribute__((ext_vector_type(4))) float fx4;

#define GLOAD16(gsrc, ldst) __builtin_amdgcn_global_load_lds( \
    (const __attribute__((address_space(1))) void*)(gsrc),    \
    (__attribute__((address_space(3))) void*)(ldst), 16, 0, 0)

__device__ __forceinline__ float gelu_f(float x) {
    return 0.5f * x * (1.0f + erff(x * 0.70710678118654752f));
}

// ---------------------------------------------------------------------------
// Patch extraction + LayerNorm -> bf16. Coalesced float4 loads staged via LDS.
// ---------------------------------------------------------------------------
__global__ __launch_bounds__(256) void patch_ln_k(const float* __restrict__ x,
                                                  __hip_bfloat16* __restrict__ out,
                                                  const float* __restrict__ g,
                                                  const float* __restrict__ bt) {
    const int r = blockIdx.x;          // 0..12543
    const int t = threadIdx.x;
    const int b = r / 196, p = r % 196;
    const int ph = p / 14, pw = p % 14;

    __shared__ float px[768];
    if (t < 192) {
        int rr = t >> 2, seg = t & 3;
        int c = rr >> 4, h1 = rr & 15;
        const float* src = x + (((size_t)b * 3 + c) * 224 + (ph * 16 + h1)) * 224
                             + pw * 16 + seg * 4;
        float4 v4 = *(const float4*)src;
        px[(h1 * 16 + seg * 4 + 0) * 3 + c] = v4.x;
        px[(h1 * 16 + seg * 4 + 1) * 3 + c] = v4.y;
        px[(h1 * 16 + seg * 4 + 2) * 3 + c] = v4.z;
        px[(h1 * 16 + seg * 4 + 3) * 3 + c] = v4.w;
    }
    __syncthreads();

    float v[3];
    #pragma unroll
    for (int i = 0; i < 3; ++i) v[i] = px[t + i * 256];
    float s = v[0] + v[1] + v[2];
    float sq = v[0]*v[0] + v[1]*v[1] + v[2]*v[2];
    #pragma unroll
    for (int off = 32; off; off >>= 1) { s += __shfl_xor(s, off); sq += __shfl_xor(sq, off); }
    __shared__ float ss[4], s2[4];
    const int w = t >> 6;
    if ((t & 63) == 0) { ss[w] = s; s2[w] = sq; }
    __syncthreads();
    s  = ss[0] + ss[1] + ss[2] + ss[3];
    sq = s2[0] + s2[1] + s2[2] + s2[3];
    const float inv = 1.0f / 768.0f;
    float mu = s * inv;
    float var = sq * inv - mu * mu;
    float rstd = rsqrtf(var + 1e-5f);
    __hip_bfloat16* o = out + (size_t)r * 768;
    #pragma unroll
    for (int i = 0; i < 3; ++i) {
        int d = t + i * 256;
        o[d] = (__hip_bfloat16)((v[i] - mu) * rstd * g[d] + bt[d]);
    }
}

// ---------------------------------------------------------------------------
// Row LayerNorm over 768 fp32 -> OT
// ---------------------------------------------------------------------------
template <typename OT>
__global__ __launch_bounds__(256) void ln_k(const float* __restrict__ in,
                                            OT* __restrict__ out,
                                            const float* __restrict__ g,
                                            const float* __restrict__ bt) {
    const int r = blockIdx.x;
    const int t = threadIdx.x;
    const float* xr = in + (size_t)r * 768;
    float v0 = xr[t], v1 = xr[t + 256], v2 = xr[t + 512];
    float s = v0 + v1 + v2;
    float sq = v0*v0 + v1*v1 + v2*v2;
    #pragma unroll
    for (int off = 32; off; off >>= 1) { s += __shfl_xor(s, off); sq += __shfl_xor(sq, off); }
    __shared__ float ss[4], s2[4];
    const int w = t >> 6;
    if ((t & 63) == 0) { ss[w] = s; s2[w] = sq; }
    __syncthreads();
    s  = ss[0] + ss[1] + ss[2] + ss[3];
    sq = s2[0] + s2[1] + s2[2] + s2[3];
    const float inv = 1.0f / 768.0f;
    float mu = s * inv;
    float var = sq * inv - mu * mu;
    float rstd = rsqrtf(var + 1e-5f);
    OT* o = out + (size_t)r * 768;
    o[t]       = (OT)((v0 - mu) * rstd * g[t]       + bt[t]);
    o[t + 256] = (OT)((v1 - mu) * rstd * g[t + 256] + bt[t + 256]);
    o[t + 512] = (OT)((v2 - mu) * rstd * g[t + 512] + bt[t + 512]);
}

// ---------------------------------------------------------------------------
// LN of CLS rows only -> bf16 [128][768] (rows 64..127 zeroed)
// ---------------------------------------------------------------------------
__global__ __launch_bounds__(256) void ln_cls_k(const float* __restrict__ in,
                                                __hip_bfloat16* __restrict__ out,
                                                const float* __restrict__ g,
                                                const float* __restrict__ bt) {
    const int b = blockIdx.x;   // 0..127
    const int t = threadIdx.x;
    if (b >= 64) {
        #pragma unroll
        for (int i = 0; i < 3; ++i) out[(size_t)b * 768 + t + i * 256] = (__hip_bfloat16)0.0f;
        return;
    }
    const float* xr = in + (size_t)b * 197 * 768;
    float v0 = xr[t], v1 = xr[t + 256], v2 = xr[t + 512];
    float s = v0 + v1 + v2;
    float sq = v0*v0 + v1*v1 + v2*v2;
    #pragma unroll
    for (int off = 32; off; off >>= 1) { s += __shfl_xor(s, off); sq += __shfl_xor(sq, off); }
    __shared__ float ss[4], s2[4];
    const int w = t >> 6;
    if ((t & 63) == 0) { ss[w] = s; s2[w] = sq; }
    __syncthreads();
    s  = ss[0] + ss[1] + ss[2] + ss[3];
    sq = s2[0] + s2[1] + s2[2] + s2[3];
    const float inv = 1.0f / 768.0f;
    float mu = s * inv;
    float var = sq * inv - mu * mu;
    float rstd = rsqrtf(var + 1e-5f);
    __hip_bfloat16* o = out + (size_t)b * 768;
    o[t]       = (__hip_bfloat16)((v0 - mu) * rstd * g[t]       + bt[t]);
    o[t + 256] = (__hip_bfloat16)((v1 - mu) * rstd * g[t + 256] + bt[t + 256]);
    o[t + 512] = (__hip_bfloat16)((v2 - mu) * rstd * g[t + 512] + bt[t + 512]);
}

// ---------------------------------------------------------------------------
// z = concat(cls, p_ln) + pos  -> [64,197,768] fp32
// ---------------------------------------------------------------------------
__global__ __launch_bounds__(256) void build_z_k(const float* __restrict__ pln,
                                                 const float* __restrict__ cls,
                                                 const float* __restrict__ pos,
                                                 float* __restrict__ z) {
    size_t idx = (size_t)blockIdx.x * 256 + threadIdx.x;
    int d  = idx % 768;
    size_t tkb = idx / 768;
    int tk = tkb % 197;
    int b  = tkb / 197;
    float v = (tk == 0) ? cls[d] : pln[((size_t)b * 196 + (tk - 1)) * 768 + d];
    z[idx] = v + pos[(size_t)tk * 768 + d];
}

// ---------------------------------------------------------------------------
// Weight convert + transpose: fp32 [K,N] -> bf16 [N,K], z-strided output
// ---------------------------------------------------------------------------
__global__ __launch_bounds__(256) void wconv_k(const float* __restrict__ W,
                                               __hip_bfloat16* __restrict__ Wt,
                                               int K, int N, size_t ostride) {
    __shared__ float tl[64][65];
    const int t = threadIdx.x;
    const int n0 = blockIdx.x * 64, k0 = blockIdx.y * 64;
    const size_t ibase = (size_t)blockIdx.z * K * N;
    const size_t obase = (size_t)blockIdx.z * ostride;
    #pragma unroll
    for (int i = 0; i < 16; ++i) {
        int idx = i * 256 + t;
        int kl = idx >> 6, nl = idx & 63;
        tl[kl][nl] = W[ibase + (size_t)(k0 + kl) * N + n0 + nl];
    }
    __syncthreads();
    #pragma unroll
    for (int i = 0; i < 16; ++i) {
        int idx = i * 256 + t;
        int nl = idx >> 6, kl = idx & 63;
        Wt[obase + (size_t)(n0 + nl) * K + k0 + kl] = (__hip_bfloat16)tl[kl][nl];
    }
}

// ---------------------------------------------------------------------------
// W_head transpose: fp32 [768][1000] -> bf16 [1024][768], pad rows zeroed
// ---------------------------------------------------------------------------
__global__ __launch_bounds__(256) void whT_k(const float* __restrict__ W,
                                             __hip_bfloat16* __restrict__ Wt) {
    __shared__ float tl[64][65];
    const int t = threadIdx.x;
    const int n0 = blockIdx.x * 64, k0 = blockIdx.y * 64;
    #pragma unroll
    for (int i = 0; i < 16; ++i) {
        int idx = i * 256 + t;
        int kl = idx >> 6, nl = idx & 63;
        int n = n0 + nl;
        tl[kl][nl] = (n < 1000) ? W[(size_t)(k0 + kl) * 1000 + n] : 0.f;
    }
    __syncthreads();
    #pragma unroll
    for (int i = 0; i < 16; ++i) {
        int idx = i * 256 + t;
        int nl = idx >> 6, kl = idx & 63;
        Wt[(size_t)(n0 + nl) * 768 + k0 + kl] = (__hip_bfloat16)tl[kl][nl];
    }
}

// ---------------------------------------------------------------------------
// 128x128 bf16 MFMA GEMM, BK=64 (kept for the small head GEMM)
// ---------------------------------------------------------------------------
template <int EPI, typename OT>
__global__ __launch_bounds__(256) void mgemm_k(const __hip_bfloat16* __restrict__ A,
                                               const __hip_bfloat16* __restrict__ Wt,
                                               const float* __restrict__ bias,
                                               const float* __restrict__ resid,
                                               OT* __restrict__ C,
                                               int M, int N, int K) {
    __shared__ __align__(16) char sA[16384];
    __shared__ __align__(16) char sB[16384];
    const int t = threadIdx.x;
    const int lane = t & 63, w = t >> 6;
    const int wr = w >> 1, wc = w & 1;
    const int lrow = lane & 15, lgr = lane >> 4;
    const int bm = blockIdx.y * 128, bn = blockIdx.x * 128;

    const __hip_bfloat16* aSrc[4];
    const __hip_bfloat16* bSrc[4];
    #pragma unroll
    for (int i = 0; i < 4; ++i) {
        int q = t + i * 256;          // 0..1023
        int r = q >> 3, c = q & 7;
        int gc = c ^ (r & 7);
        aSrc[i] = A  + (size_t)(bm + r) * K + gc * 8;
        bSrc[i] = Wt + (size_t)(bn + r) * K + gc * 8;
    }

    int aoff[4][2], boff[4][2];
    #pragma unroll
    for (int m = 0; m < 4; ++m) {
        int ra = wr * 64 + m * 16 + lrow;
        int rb = wc * 64 + m * 16 + lrow;
        #pragma unroll
        for (int ks = 0; ks < 2; ++ks) {
            aoff[m][ks] = ra * 128 + (((ks * 4 + lgr) ^ (ra & 7)) << 4);
            boff[m][ks] = rb * 128 + (((ks * 4 + lgr) ^ (rb & 7)) << 4);
        }
    }

    fx4 acc[4][4];
    #pragma unroll
    for (int m = 0; m < 4; ++m)
        #pragma unroll
        for (int n = 0; n < 4; ++n)
            #pragma unroll
            for (int e = 0; e < 4; ++e) acc[m][n][e] = 0.f;

    for (int k0 = 0; k0 < K; k0 += 64) {
        #pragma unroll
        for (int i = 0; i < 4; ++i) GLOAD16(aSrc[i] + k0, sA + (t + i * 256) * 16);
        #pragma unroll
        for (int i = 0; i < 4; ++i) GLOAD16(bSrc[i] + k0, sB + (t + i * 256) * 16);
        __syncthreads();
        #pragma unroll
        for (int ks = 0; ks < 2; ++ks) {
            bfx8 av[4], bv[4];
            #pragma unroll
            for (int m = 0; m < 4; ++m) {
                av[m] = *(const bfx8*)(sA + aoff[m][ks]);
                bv[m] = *(const bfx8*)(sB + boff[m][ks]);
            }
            #pragma unroll
            for (int m = 0; m < 4; ++m)
                #pragma unroll
                for (int n = 0; n < 4; ++n)
                    acc[m][n] = __builtin_amdgcn_mfma_f32_16x16x32_bf16(av[m], bv[n], acc[m][n], 0, 0, 0);
        }
        __syncthreads();
    }

    #pragma unroll
    for (int m = 0; m < 4; ++m) {
        #pragma unroll
        for (int n = 0; n < 4; ++n) {
            const int col = bn + wc * 64 + n * 16 + lrow;
            float bv2 = (EPI >= 1) ? bias[col] : 0.f;
            #pragma unroll
            for (int e = 0; e < 4; ++e) {
                const int row = bm + wr * 64 + m * 16 + lgr * 4 + e;
                if (row < M) {
                    float v = acc[m][n][e] + bv2;
                    if (EPI == 2) v = gelu_f(v);
                    if (EPI == 3) v += resid[(size_t)row * N + col];
                    C[(size_t)row * N + col] = (OT)v;
                }
            }
        }
    }
}

// ---------------------------------------------------------------------------
// 256x192 bf16 MFMA GEMM, BK=64, depth-2 counted-vmcnt pipeline.
// A: 3 LDS buffers (32KB each) -> no overwrite hazard, frags read lazily.
// B: 2 LDS buffers (24KB each) -> frags pre-read to regs + hazard barrier.
// Raw s_barrier only; vmcnt(7) in steady state (stage(kt+2) stays in flight).
// XCD-bijective blockIdx swizzle (m204). 8 waves (2x4). N%192==0, K%64==0.
// A must have ceil(M/256)*256 readable rows.
// ---------------------------------------------------------------------------
template <int EPI, typename OT>
__global__ __launch_bounds__(512, 2) void mgemm256_k(const __hip_bfloat16* __restrict__ A,
                                                     const __hip_bfloat16* __restrict__ Wt,
                                                     const float* __restrict__ bias,
                                                     const float* __restrict__ resid,
                                                     OT* __restrict__ C,
                                                     int M, int N, int K) {
    __shared__ __align__(16) char sA[3 * 32768];   // 96 KiB
    __shared__ __align__(16) char sB[2 * 24576];   // 48 KiB
    const int t = threadIdx.x;            // 0..511
    const int lane = t & 63, w = t >> 6;  // 8 waves
    const int wr = w >> 2, wc = w & 3;    // 2 x 4 -> 128 x 48 per wave
    const int lrow = lane & 15, lgr = lane >> 4;

    // ---- bijective XCD swizzle (T1, m204) ----
    const int gx = gridDim.x, nwg = gx * gridDim.y;
    const int q8 = nwg >> 3, r8 = nwg & 7;
    const int orig = blockIdx.y * gx + blockIdx.x;
    const int xcd = orig & 7, idx8 = orig >> 3;
    const int swz = (xcd < r8 ? xcd * (q8 + 1) : r8 * (q8 + 1) + (xcd - r8) * q8) + idx8;
    const int bm = (swz / gx) * 256;
    const int bn = (swz % gx) * 192;

    const __hip_bfloat16* aSrc[4];
    const __hip_bfloat16* bSrc[3];
    #pragma unroll
    for (int i = 0; i < 4; ++i) {
        int q = t + i * 512;              // 0..2047 -> 256 rows x 8 chunks
        int r = q >> 3, c = q & 7;
        int gc = c ^ (r & 7);
        aSrc[i] = A + (size_t)(bm + r) * K + gc * 8;
    }
    #pragma unroll
    for (int i = 0; i < 3; ++i) {
        int q = t + i * 512;              // 0..1535 -> 192 rows x 8 chunks
        int r = q >> 3, c = q & 7;
        int gc = c ^ (r & 7);
        bSrc[i] = Wt + (size_t)(bn + r) * K + gc * 8;
    }

    int aoff[8][2], boff[3][2];
    #pragma unroll
    for (int m = 0; m < 8; ++m) {
        int ra = wr * 128 + m * 16 + lrow;
        #pragma unroll
        for (int ks = 0; ks < 2; ++ks)
            aoff[m][ks] = ra * 128 + (((ks * 4 + lgr) ^ (ra & 7)) << 4);
    }
    #pragma unroll
    for (int n = 0; n < 3; ++n) {
        int rb = wc * 48 + n * 16 + lrow;
        #pragma unroll
        for (int ks = 0; ks < 2; ++ks)
            boff[n][ks] = rb * 128 + (((ks * 4 + lgr) ^ (rb & 7)) << 4);
    }

    fx4 acc[8][3];
    #pragma unroll
    for (int m = 0; m < 8; ++m)
        #pragma unroll
        for (int n = 0; n < 3; ++n)
            #pragma unroll
            for (int e = 0; e < 4; ++e) acc[m][n][e] = 0.f;

    const int NK = K >> 6;

    // ---- prologue: stage k-tiles 0 and 1 ----
    #pragma unroll
    for (int i = 0; i < 4; ++i) GLOAD16(aSrc[i], sA + (t + i * 512) * 16);
    #pragma unroll
    for (int i = 0; i < 3; ++i) GLOAD16(bSrc[i], sB + (t + i * 512) * 16);
    #pragma unroll
    for (int i = 0; i < 4; ++i) GLOAD16(aSrc[i] + 64, sA + 32768 + (t + i * 512) * 16);
    #pragma unroll
    for (int i = 0; i < 3; ++i) GLOAD16(bSrc[i] + 64, sB + 24576 + (t + i * 512) * 16);
    asm volatile("s_waitcnt vmcnt(7)" ::: "memory");   // tile 0 resident
    __builtin_amdgcn_sched_barrier(0);
    __builtin_amdgcn_s_barrier();

    for (int kt = 0; kt < NK; ++kt) {
        const char* bB = sB + (kt & 1) * 24576;
        // pre-read ALL B fragments of this K-tile into registers
        bfx8 bv[3][2];
        #pragma unroll
        for (int n = 0; n < 3; ++n)
            #pragma unroll
            for (int ks = 0; ks < 2; ++ks)
                bv[n][ks] = *(const bfx8*)(bB + boff[n][ks]);
        asm volatile("s_waitcnt lgkmcnt(0)" ::: "memory");
        __builtin_amdgcn_sched_barrier(0);
        __builtin_amdgcn_s_barrier();       // all waves done reading sB[kt&1]
        __builtin_amdgcn_sched_barrier(0);

        // stage k-tile kt+2 (A -> rotating 3rd buffer, B -> the buffer just freed)
        if (kt + 2 < NK) {
            const int ab = (kt + 2) % 3;
            const int kk = (kt + 2) * 64;
            #pragma unroll
            for (int i = 0; i < 4; ++i) GLOAD16(aSrc[i] + kk, sA + ab * 32768 + (t + i * 512) * 16);
            #pragma unroll
            for (int i = 0; i < 3; ++i) GLOAD16(bSrc[i] + kk, sB + (kt & 1) * 24576 + (t + i * 512) * 16);
        }

        // compute: A frags read lazily from sA[kt%3] (not being staged)
        const char* bA = sA + (kt % 3) * 32768;
        __builtin_amdgcn_s_setprio(1);
        #pragma unroll
        for (int m = 0; m < 8; ++m) {
            bfx8 a0 = *(const bfx8*)(bA + aoff[m][0]);
            bfx8 a1 = *(const bfx8*)(bA + aoff[m][1]);
            #pragma unroll
            for (int n = 0; n < 3; ++n) {
                acc[m][n] = __builtin_amdgcn_mfma_f32_16x16x32_bf16(a0, bv[n][0], acc[m][n], 0, 0, 0);
                acc[m][n] = __builtin_amdgcn_mfma_f32_16x16x32_bf16(a1, bv[n][1], acc[m][n], 0, 0, 0);
            }
        }
        __builtin_amdgcn_s_setprio(0);
        __builtin_amdgcn_sched_barrier(0);

        // wait for k-tile kt+1 residency (stage kt+2 stays in flight), publish
        if (kt + 1 < NK) {
            if (kt + 2 < NK) asm volatile("s_waitcnt vmcnt(7)" ::: "memory");
            else             asm volatile("s_waitcnt vmcnt(0)" ::: "memory");
            __builtin_amdgcn_sched_barrier(0);
            __builtin_amdgcn_s_barrier();
        }
    }

    // ---- epilogue ----
    #pragma unroll
    for (int m = 0; m < 8; ++m) {
        #pragma unroll
        for (int n = 0; n < 3; ++n) {
            const int col = bn + wc * 48 + n * 16 + lrow;
            float bv2 = (EPI >= 1) ? bias[col] : 0.f;
            #pragma unroll
            for (int e = 0; e < 4; ++e) {
                const int row = bm + wr * 128 + m * 16 + lgr * 4 + e;
                if (row < M) {
                    float v = acc[m][n][e] + bv2;
                    if (EPI == 2) v = gelu_f(v);
                    if (EPI == 3) v += resid[(size_t)row * N + col];
                    C[(size_t)row * N + col] = (OT)v;
                }
            }
        }
    }
}

// ---------------------------------------------------------------------------
// MFMA fused attention on fused QKV buffer (row stride 2304).
// ---------------------------------------------------------------------------
__global__ __launch_bounds__(256) void attn_k(const __hip_bfloat16* __restrict__ QKV,
                                              __hip_bfloat16* __restrict__ O) {
    __shared__ __align__(16) char Ks[224 * 128];   // 28672
    __shared__ __align__(16) char VTs[64 * 464];   // 29696
    __shared__ __align__(16) char Ps[4][7424];     // 4 x (16 rows x 464B)

    const int h = blockIdx.x;
    const int b = blockIdx.y;
    const int t = threadIdx.x;
    const int lane = t & 63, w = t >> 6;
    const int rho = lane & 15, g = lane >> 4;
    const size_t base = (size_t)b * NTOK * 2304;
    const int qoff = h * 64, koff = 768 + h * 64, voff = 1536 + h * 64;
    const size_t obase = ((size_t)b * NTOK) * 768 + h * 64;

    #pragma unroll
    for (int i = 0; i < 7; ++i) {
        int q = t + i * 256;            // 0..1791
        int j = q >> 3, c = q & 7;
        int gc = c ^ (j & 7);
        GLOAD16(QKV + base + (size_t)j * 2304 + koff + gc * 8, Ks + q * 16);
    }
    #pragma unroll
    for (int i = 0; i < 7; ++i) {
        int q = t + i * 256;
        int tok = q >> 3, c = q & 7;
        bfx8 vv = {0, 0, 0, 0, 0, 0, 0, 0};
        if (tok < NTOK) vv = *(const bfx8*)(QKV + base + (size_t)tok * 2304 + voff + c * 8);
        #pragma unroll
        for (int u = 0; u < 8; ++u)
            *(unsigned short*)(VTs + (c * 8 + u) * 464 + tok * 2) = (unsigned short)vv[u];
    }
    __syncthreads();

    char* Pw = Ps[w];

    for (int qt = w; qt < 13; qt += 4) {
        const int q0 = qt * 16;
        fx4 s[13];
        #pragma unroll
        for (int nt = 0; nt < 13; ++nt)
            #pragma unroll
            for (int e = 0; e < 4; ++e) s[nt][e] = 0.f;
        #pragma unroll
        for (int ks = 0; ks < 2; ++ks) {
            bfx8 av = *(const bfx8*)(QKV + base + (size_t)(q0 + rho) * 2304 + qoff + ks * 32 + g * 8);
            #pragma unroll
            for (int nt = 0; nt < 13; ++nt) {
                int r = nt * 16 + rho;
                bfx8 bv = *(const bfx8*)(Ks + r * 128 + (((ks * 4 + g) ^ (r & 7)) << 4));
                s[nt] = __builtin_amdgcn_mfma_f32_16x16x32_bf16(av, bv, s[nt], 0, 0, 0);
            }
        }
        float mx[4] = {-1e30f, -1e30f, -1e30f, -1e30f};
        #pragma unroll
        for (int nt = 0; nt < 13; ++nt) {
            #pragma unroll
            for (int e = 0; e < 4; ++e) {
                float v = s[nt][e] * 0.125f;
                if (nt == 12 && rho >= 5) v = -1e30f;
                s[nt][e] = v;
                mx[e] = fmaxf(mx[e], v);
            }
        }
        #pragma unroll
        for (int off = 1; off < 16; off <<= 1)
            #pragma unroll
            for (int e = 0; e < 4; ++e) mx[e] = fmaxf(mx[e], __shfl_xor(mx[e], off));
        float sm[4] = {0.f, 0.f, 0.f, 0.f};
        #pragma unroll
        for (int nt = 0; nt < 13; ++nt)
            #pragma unroll
            for (int e = 0; e < 4; ++e) {
                float p = __expf(s[nt][e] - mx[e]);
                s[nt][e] = p;
                sm[e] += p;
            }
        #pragma unroll
        for (int off = 1; off < 16; off <<= 1)
            #pragma unroll
            for (int e = 0; e < 4; ++e) sm[e] += __shfl_xor(sm[e], off);
        float inv[4];
        #pragma unroll
        for (int e = 0; e < 4; ++e) inv[e] = 1.0f / sm[e];

        #pragma unroll
        for (int nt = 0; nt < 13; ++nt)
            #pragma unroll
            for (int e = 0; e < 4; ++e) {
                int row = g * 4 + e;
                int col = nt * 16 + rho;
                *(__hip_bfloat16*)(Pw + row * 464 + col * 2) =
                    (__hip_bfloat16)(s[nt][e] * inv[e]);
            }
        #pragma unroll
        for (int e = 0; e < 4; ++e)
            *(__hip_bfloat16*)(Pw + (g * 4 + e) * 464 + (208 + rho) * 2) = (__hip_bfloat16)0.0f;

        __builtin_amdgcn_sched_barrier(0);
        asm volatile("s_waitcnt lgkmcnt(0)" ::: "memory");
        __builtin_amdgcn_sched_barrier(0);

        #pragma unroll
        for (int dt = 0; dt < 4; ++dt) {
            fx4 o;
            #pragma unroll
            for (int e = 0; e < 4; ++e) o[e] = 0.f;
            #pragma unroll
            for (int ks = 0; ks < 7; ++ks) {
                bfx8 pa = *(const bfx8*)(Pw + rho * 464 + (ks * 4 + g) * 16);
                bfx8 bv = *(const bfx8*)(VTs + (dt * 16 + rho) * 464 + (ks * 4 + g) * 16);
                o = __builtin_amdgcn_mfma_f32_16x16x32_bf16(pa, bv, o, 0, 0, 0);
            }
            #pragma unroll
            for (int e = 0; e < 4; ++e) {
                int qrow = q0 + g * 4 + e;
                if (qrow < NTOK)
                    O[obase + (size_t)qrow * 768 + dt * 16 + rho] = (__hip_bfloat16)o[e];
            }
        }
    }
}

// ---------------------------------------------------------------------------
// Head softmax: out[b,:] = softmax(logits[b,:1000] + b_head)
// ---------------------------------------------------------------------------
__global__ __launch_bounds__(256) void shead_k(const float* __restrict__ logits,
                                               const float* __restrict__ bh,
                                               float* __restrict__ out) {
    const int b = blockIdx.x;
    const int t = threadIdx.x;
    __shared__ float lg[1000];
    __shared__ float red[4];

    for (int c = t; c < 1000; c += 256) lg[c] = logits[(size_t)b * 1024 + c] + bh[c];
    __syncthreads();

    float m = -1e30f;
    for (int c = t; c < 1000; c += 256) m = fmaxf(m, lg[c]);
    #pragma unroll
    for (int off = 32; off; off >>= 1) m = fmaxf(m, __shfl_xor(m, off));
    if ((t & 63) == 0) red[t >> 6] = m;
    __syncthreads();
    m = fmaxf(fmaxf(red[0], red[1]), fmaxf(red[2], red[3]));
    __syncthreads();

    float sum = 0.f;
    for (int c = t; c < 1000; c += 256) sum += __expf(lg[c] - m);
    #pragma unroll
    for (int off = 32; off; off >>= 1) sum += __shfl_xor(sum, off);
    if ((t & 63) == 0) red[t >> 6] = sum;
    __syncthreads();
    sum = red[0] + red[1] + red[2] + red[3];
    const float invs = 1.0f / sum;
    for (int c = t; c < 1000; c += 256) out[(size_t)b * 1000 + c] = __expf(lg[c] - m) * invs;
}

// ---------------------------------------------------------------------------
// Driver
// ---------------------------------------------------------------------------
extern "C" void kernel_launch(void* const* d_in, const int* in_sizes, int n_in,
                              void* d_out, int out_size, void* d_ws, size_t ws_size,
                              hipStream_t stream) {
    const float* x        = (const float*)d_in[0];
    const float* ln_p_g   = (const float*)d_in[1];
    const float* ln_p_b   = (const float*)d_in[2];
    const float* W_patch  = (const float*)d_in[3];
    const float* b_patch  = (const float*)d_in[4];
    const float* ln_e_g   = (const float*)d_in[5];
    const float* ln_e_b   = (const float*)d_in[6];
    const float* pos_emb  = (const float*)d_in[7];
    const float* cls_tok  = (const float*)d_in[8];
    const float* ln_a_g   = (const float*)d_in[9];
    const float* ln_a_b   = (const float*)d_in[10];
    const float* Wq       = (const float*)d_in[11];
    const float* Wk       = (const float*)d_in[12];
    const float* Wv       = (const float*)d_in[13];
    const float* Wo       = (const float*)d_in[14];
    const float* bo       = (const float*)d_in[15];
    const float* ln_f_g   = (const float*)d_in[16];
    const float* ln_f_b   = (const float*)d_in[17];
    const float* W1       = (const float*)d_in[18];
    const float* b1       = (const float*)d_in[19];
    const float* W2       = (const float*)d_in[20];
    const float* b2       = (const float*)d_in[21];
    const float* ln_out_g = (const float*)d_in[22];
    const float* ln_out_b = (const float*)d_in[23];
    const float* W_head   = (const float*)d_in[24];
    const float* b_head   = (const float*)d_in[25];

    typedef __hip_bfloat16 bf;
    const int M  = 12608;               // 64*197
    const int MP = 12800;               // padded to 50*256
    char* p = (char*)d_ws;

    float* Z   = (float*)p;            p += (size_t)MP * 768 * 4;      // fp32 residual
    bf* XA     = (bf*)p;               p += (size_t)MP * 768 * 2;      // LN out (bf16)
    bf* QKV    = (bf*)p;               p += (size_t)MP * 2304 * 2;     // fused q,k,v
    bf* OB     = (bf*)p;               p += (size_t)MP * 768 * 2;
    char* FFHc = p;                    p += (size_t)MP * 3072 * 2;     // bf16 GELU buf
    bf* FFH    = (bf*)FFHc;
    float* PE  = (float*)FFHc;                                          // alias: patch-embed fp32
    float* E2  = (float*)(FFHc + (size_t)MP * 768 * 4);                 // alias: ln_e out fp32
    bf* WQKVT  = (bf*)p;               p += (size_t)12 * 2304 * 768 * 2;
    bf* WoT    = (bf*)p;               p += (size_t)12 * 768 * 768 * 2;
    bf* W1T    = (bf*)p;               p += (size_t)12 * 3072 * 768 * 2;
    bf* W2T    = (bf*)p;               p += (size_t)12 * 768 * 3072 * 2;
    bf* WpT    = (bf*)p;               p += (size_t)768 * 768 * 2;
    bf* WhT    = (bf*)p;               p += (size_t)1024 * 768 * 2;
    bf* CLS    = (bf*)p;               p += (size_t)128 * 768 * 2;
    float* LOG = (float*)p;            p += (size_t)64 * 1024 * 4;

    const size_t QKVS = (size_t)2304 * 768;

    // weight convert + transpose (every launch)
    wconv_k<<<dim3(12, 12, 12), 256, 0, stream>>>(Wq, WQKVT,             768, 768,  QKVS);
    wconv_k<<<dim3(12, 12, 12), 256, 0, stream>>>(Wk, WQKVT + 768 * 768, 768, 768,  QKVS);
    wconv_k<<<dim3(12, 12, 12), 256, 0, stream>>>(Wv, WQKVT + 1536 * 768,768, 768,  QKVS);
    wconv_k<<<dim3(12, 12, 12), 256, 0, stream>>>(Wo, WoT,  768, 768,  (size_t)768 * 768);
    wconv_k<<<dim3(48, 12, 12), 256, 0, stream>>>(W1, W1T,  768, 3072, (size_t)3072 * 768);
    wconv_k<<<dim3(12, 48, 12), 256, 0, stream>>>(W2, W2T,  3072, 768, (size_t)768 * 3072);
    wconv_k<<<dim3(12, 12, 1),  256, 0, stream>>>(W_patch, WpT, 768, 768, 0);
    whT_k  <<<dim3(16, 12),     256, 0, stream>>>(W_head, WhT);

    // patch embed pipeline (12544 = 49*256 exactly)
    patch_ln_k<<<12544, 256, 0, stream>>>(x, XA, ln_p_g, ln_p_b);
    mgemm256_k<1, float><<<dim3(4, 49), 512, 0, stream>>>(XA, WpT, b_patch, nullptr, PE, 12544, 768, 768);
    ln_k<float><<<12544, 256, 0, stream>>>(PE, E2, ln_e_g, ln_e_b);
    build_z_k<<<37824, 256, 0, stream>>>(E2, cls_tok, pos_emb, Z);

    for (int i = 0; i < 12; ++i) {
        bf* WQKVT_i = WQKVT + (size_t)i * QKVS;
        bf* WoT_i   = WoT + (size_t)i * 768 * 768;
        bf* W1T_i   = W1T + (size_t)i * 3072 * 768;
        bf* W2T_i   = W2T + (size_t)i * 768 * 3072;

        ln_k<bf><<<M, 256, 0, stream>>>(Z, XA, ln_a_g + (size_t)i * 768, ln_a_b + (size_t)i * 768);
        mgemm256_k<0, bf><<<dim3(12, 50), 512, 0, stream>>>(XA, WQKVT_i, nullptr, nullptr, QKV, M, 2304, 768);
        attn_k<<<dim3(12, 64), 256, 0, stream>>>(QKV, OB);
        mgemm256_k<3, float><<<dim3(4, 50), 512, 0, stream>>>(OB, WoT_i, bo + (size_t)i * 768, Z, Z, M, 768, 768);
        ln_k<bf><<<M, 256, 0, stream>>>(Z, XA, ln_f_g + (size_t)i * 768, ln_f_b + (size_t)i * 768);
        mgemm256_k<2, bf><<<dim3(16, 50), 512, 0, stream>>>(XA, W1T_i, b1 + (size_t)i * 3072, nullptr, FFH, M, 3072, 768);
        mgemm256_k<3, float><<<dim3(4, 50), 512, 0, stream>>>(FFH, W2T_i, b2 + (size_t)i * 768, Z, Z, M, 768, 3072);
    }

    // head: LN(CLS rows) -> logits GEMM (128^2 kernel) -> softmax
    ln_cls_k<<<128, 256, 0, stream>>>(Z, CLS, ln_out_g, ln_out_b);
    mgemm_k<0, float><<<dim3(8, 1), 256, 0, stream>>>(CLS, WhT, nullptr, nullptr, LOG, 64, 1024, 768);
    shead_k<<<64, 256, 0, stream>>>(LOG, b_head, (float*)d_out);
}

// Round 8
// 5486.915 us; speedup vs baseline: 1.1810x; 1.1370x over previous
//
#include <hip/hip_runtime.h>
#include <hip/hip_bf16.h>
#include <math.h>

#define NTOK 197

typedef __attribute__((ext_vector_type(8))) short bfx8;
typedef __attribute__((ext_vector_type(4))) float fx4;

#define GLOAD16(gsrc, ldst) __builtin_amdgcn_global_load_lds( \
    (const __attribute__((address_space(1))) void*)(gsrc),    \
    (__attribute__((address_space(3))) void*)(ldst), 16, 0, 0)

__device__ __forceinline__ float gelu_f(float x) {
    return 0.5f * x * (1.0f + erff(x * 0.70710678118654752f));
}

// ---------------------------------------------------------------------------
// Patch extraction + LayerNorm -> bf16. Coalesced float4 loads staged via LDS.
// ---------------------------------------------------------------------------
__global__ __launch_bounds__(256) void patch_ln_k(const float* __restrict__ x,
                                                  __hip_bfloat16* __restrict__ out,
                                                  const float* __restrict__ g,
                                                  const float* __restrict__ bt) {
    const int r = blockIdx.x;          // 0..12543
    const int t = threadIdx.x;
    const int b = r / 196, p = r % 196;
    const int ph = p / 14, pw = p % 14;

    __shared__ float px[768];
    if (t < 192) {
        int rr = t >> 2, seg = t & 3;
        int c = rr >> 4, h1 = rr & 15;
        const float* src = x + (((size_t)b * 3 + c) * 224 + (ph * 16 + h1)) * 224
                             + pw * 16 + seg * 4;
        float4 v4 = *(const float4*)src;
        px[(h1 * 16 + seg * 4 + 0) * 3 + c] = v4.x;
        px[(h1 * 16 + seg * 4 + 1) * 3 + c] = v4.y;
        px[(h1 * 16 + seg * 4 + 2) * 3 + c] = v4.z;
        px[(h1 * 16 + seg * 4 + 3) * 3 + c] = v4.w;
    }
    __syncthreads();

    float v[3];
    #pragma unroll
    for (int i = 0; i < 3; ++i) v[i] = px[t + i * 256];
    float s = v[0] + v[1] + v[2];
    float sq = v[0]*v[0] + v[1]*v[1] + v[2]*v[2];
    #pragma unroll
    for (int off = 32; off; off >>= 1) { s += __shfl_xor(s, off); sq += __shfl_xor(sq, off); }
    __shared__ float ss[4], s2[4];
    const int w = t >> 6;
    if ((t & 63) == 0) { ss[w] = s; s2[w] = sq; }
    __syncthreads();
    s  = ss[0] + ss[1] + ss[2] + ss[3];
    sq = s2[0] + s2[1] + s2[2] + s2[3];
    const float inv = 1.0f / 768.0f;
    float mu = s * inv;
    float var = sq * inv - mu * mu;
    float rstd = rsqrtf(var + 1e-5f);
    __hip_bfloat16* o = out + (size_t)r * 768;
    #pragma unroll
    for (int i = 0; i < 3; ++i) {
        int d = t + i * 256;
        o[d] = (__hip_bfloat16)((v[i] - mu) * rstd * g[d] + bt[d]);
    }
}

// ---------------------------------------------------------------------------
// Row LayerNorm over 768 fp32 -> OT
// ---------------------------------------------------------------------------
template <typename OT>
__global__ __launch_bounds__(256) void ln_k(const float* __restrict__ in,
                                            OT* __restrict__ out,
                                            const float* __restrict__ g,
                                            const float* __restrict__ bt) {
    const int r = blockIdx.x;
    const int t = threadIdx.x;
    const float* xr = in + (size_t)r * 768;
    float v0 = xr[t], v1 = xr[t + 256], v2 = xr[t + 512];
    float s = v0 + v1 + v2;
    float sq = v0*v0 + v1*v1 + v2*v2;
    #pragma unroll
    for (int off = 32; off; off >>= 1) { s += __shfl_xor(s, off); sq += __shfl_xor(sq, off); }
    __shared__ float ss[4], s2[4];
    const int w = t >> 6;
    if ((t & 63) == 0) { ss[w] = s; s2[w] = sq; }
    __syncthreads();
    s  = ss[0] + ss[1] + ss[2] + ss[3];
    sq = s2[0] + s2[1] + s2[2] + s2[3];
    const float inv = 1.0f / 768.0f;
    float mu = s * inv;
    float var = sq * inv - mu * mu;
    float rstd = rsqrtf(var + 1e-5f);
    OT* o = out + (size_t)r * 768;
    o[t]       = (OT)((v0 - mu) * rstd * g[t]       + bt[t]);
    o[t + 256] = (OT)((v1 - mu) * rstd * g[t + 256] + bt[t + 256]);
    o[t + 512] = (OT)((v2 - mu) * rstd * g[t + 512] + bt[t + 512]);
}

// ---------------------------------------------------------------------------
// LN of CLS rows only -> bf16 [128][768] (rows 64..127 zeroed)
// ---------------------------------------------------------------------------
__global__ __launch_bounds__(256) void ln_cls_k(const float* __restrict__ in,
                                                __hip_bfloat16* __restrict__ out,
                                                const float* __restrict__ g,
                                                const float* __restrict__ bt) {
    const int b = blockIdx.x;   // 0..127
    const int t = threadIdx.x;
    if (b >= 64) {
        #pragma unroll
        for (int i = 0; i < 3; ++i) out[(size_t)b * 768 + t + i * 256] = (__hip_bfloat16)0.0f;
        return;
    }
    const float* xr = in + (size_t)b * 197 * 768;
    float v0 = xr[t], v1 = xr[t + 256], v2 = xr[t + 512];
    float s = v0 + v1 + v2;
    float sq = v0*v0 + v1*v1 + v2*v2;
    #pragma unroll
    for (int off = 32; off; off >>= 1) { s += __shfl_xor(s, off); sq += __shfl_xor(sq, off); }
    __shared__ float ss[4], s2[4];
    const int w = t >> 6;
    if ((t & 63) == 0) { ss[w] = s; s2[w] = sq; }
    __syncthreads();
    s  = ss[0] + ss[1] + ss[2] + ss[3];
    sq = s2[0] + s2[1] + s2[2] + s2[3];
    const float inv = 1.0f / 768.0f;
    float mu = s * inv;
    float var = sq * inv - mu * mu;
    float rstd = rsqrtf(var + 1e-5f);
    __hip_bfloat16* o = out + (size_t)b * 768;
    o[t]       = (__hip_bfloat16)((v0 - mu) * rstd * g[t]       + bt[t]);
    o[t + 256] = (__hip_bfloat16)((v1 - mu) * rstd * g[t + 256] + bt[t + 256]);
    o[t + 512] = (__hip_bfloat16)((v2 - mu) * rstd * g[t + 512] + bt[t + 512]);
}

// ---------------------------------------------------------------------------
// z = concat(cls, p_ln) + pos  -> [64,197,768] fp32
// ---------------------------------------------------------------------------
__global__ __launch_bounds__(256) void build_z_k(const float* __restrict__ pln,
                                                 const float* __restrict__ cls,
                                                 const float* __restrict__ pos,
                                                 float* __restrict__ z) {
    size_t idx = (size_t)blockIdx.x * 256 + threadIdx.x;
    int d  = idx % 768;
    size_t tkb = idx / 768;
    int tk = tkb % 197;
    int b  = tkb / 197;
    float v = (tk == 0) ? cls[d] : pln[((size_t)b * 196 + (tk - 1)) * 768 + d];
    z[idx] = v + pos[(size_t)tk * 768 + d];
}

// ---------------------------------------------------------------------------
// Weight convert + transpose: fp32 [K,N] -> bf16 [N,K], z-strided output
// ---------------------------------------------------------------------------
__global__ __launch_bounds__(256) void wconv_k(const float* __restrict__ W,
                                               __hip_bfloat16* __restrict__ Wt,
                                               int K, int N, size_t ostride) {
    __shared__ float tl[64][65];
    const int t = threadIdx.x;
    const int n0 = blockIdx.x * 64, k0 = blockIdx.y * 64;
    const size_t ibase = (size_t)blockIdx.z * K * N;
    const size_t obase = (size_t)blockIdx.z * ostride;
    #pragma unroll
    for (int i = 0; i < 16; ++i) {
        int idx = i * 256 + t;
        int kl = idx >> 6, nl = idx & 63;
        tl[kl][nl] = W[ibase + (size_t)(k0 + kl) * N + n0 + nl];
    }
    __syncthreads();
    #pragma unroll
    for (int i = 0; i < 16; ++i) {
        int idx = i * 256 + t;
        int nl = idx >> 6, kl = idx & 63;
        Wt[obase + (size_t)(n0 + nl) * K + k0 + kl] = (__hip_bfloat16)tl[kl][nl];
    }
}

// ---------------------------------------------------------------------------
// W_head transpose: fp32 [768][1000] -> bf16 [1024][768], pad rows zeroed
// ---------------------------------------------------------------------------
__global__ __launch_bounds__(256) void whT_k(const float* __restrict__ W,
                                             __hip_bfloat16* __restrict__ Wt) {
    __shared__ float tl[64][65];
    const int t = threadIdx.x;
    const int n0 = blockIdx.x * 64, k0 = blockIdx.y * 64;
    #pragma unroll
    for (int i = 0; i < 16; ++i) {
        int idx = i * 256 + t;
        int kl = idx >> 6, nl = idx & 63;
        int n = n0 + nl;
        tl[kl][nl] = (n < 1000) ? W[(size_t)(k0 + kl) * 1000 + n] : 0.f;
    }
    __syncthreads();
    #pragma unroll
    for (int i = 0; i < 16; ++i) {
        int idx = i * 256 + t;
        int nl = idx >> 6, kl = idx & 63;
        Wt[(size_t)(n0 + nl) * 768 + k0 + kl] = (__hip_bfloat16)tl[kl][nl];
    }
}

// ---------------------------------------------------------------------------
// 128x128 bf16 MFMA GEMM, BK=64 (round-5 known-good; used for N=768 GEMMs)
// ---------------------------------------------------------------------------
template <int EPI, typename OT>
__global__ __launch_bounds__(256) void mgemm_k(const __hip_bfloat16* __restrict__ A,
                                               const __hip_bfloat16* __restrict__ Wt,
                                               const float* __restrict__ bias,
                                               const float* __restrict__ resid,
                                               OT* __restrict__ C,
                                               int M, int N, int K) {
    __shared__ __align__(16) char sA[16384];
    __shared__ __align__(16) char sB[16384];
    const int t = threadIdx.x;
    const int lane = t & 63, w = t >> 6;
    const int wr = w >> 1, wc = w & 1;
    const int lrow = lane & 15, lgr = lane >> 4;
    const int bm = blockIdx.y * 128, bn = blockIdx.x * 128;

    const __hip_bfloat16* aSrc[4];
    const __hip_bfloat16* bSrc[4];
    #pragma unroll
    for (int i = 0; i < 4; ++i) {
        int q = t + i * 256;          // 0..1023
        int r = q >> 3, c = q & 7;
        int gc = c ^ (r & 7);
        aSrc[i] = A  + (size_t)(bm + r) * K + gc * 8;
        bSrc[i] = Wt + (size_t)(bn + r) * K + gc * 8;
    }

    int aoff[4][2], boff[4][2];
    #pragma unroll
    for (int m = 0; m < 4; ++m) {
        int ra = wr * 64 + m * 16 + lrow;
        int rb = wc * 64 + m * 16 + lrow;
        #pragma unroll
        for (int ks = 0; ks < 2; ++ks) {
            aoff[m][ks] = ra * 128 + (((ks * 4 + lgr) ^ (ra & 7)) << 4);
            boff[m][ks] = rb * 128 + (((ks * 4 + lgr) ^ (rb & 7)) << 4);
        }
    }

    fx4 acc[4][4];
    #pragma unroll
    for (int m = 0; m < 4; ++m)
        #pragma unroll
        for (int n = 0; n < 4; ++n)
            #pragma unroll
            for (int e = 0; e < 4; ++e) acc[m][n][e] = 0.f;

    for (int k0 = 0; k0 < K; k0 += 64) {
        #pragma unroll
        for (int i = 0; i < 4; ++i) GLOAD16(aSrc[i] + k0, sA + (t + i * 256) * 16);
        #pragma unroll
        for (int i = 0; i < 4; ++i) GLOAD16(bSrc[i] + k0, sB + (t + i * 256) * 16);
        __syncthreads();
        #pragma unroll
        for (int ks = 0; ks < 2; ++ks) {
            bfx8 av[4], bv[4];
            #pragma unroll
            for (int m = 0; m < 4; ++m) {
                av[m] = *(const bfx8*)(sA + aoff[m][ks]);
                bv[m] = *(const bfx8*)(sB + boff[m][ks]);
            }
            #pragma unroll
            for (int m = 0; m < 4; ++m)
                #pragma unroll
                for (int n = 0; n < 4; ++n)
                    acc[m][n] = __builtin_amdgcn_mfma_f32_16x16x32_bf16(av[m], bv[n], acc[m][n], 0, 0, 0);
        }
        __syncthreads();
    }

    #pragma unroll
    for (int m = 0; m < 4; ++m) {
        #pragma unroll
        for (int n = 0; n < 4; ++n) {
            const int col = bn + wc * 64 + n * 16 + lrow;
            float bv2 = (EPI >= 1) ? bias[col] : 0.f;
            #pragma unroll
            for (int e = 0; e < 4; ++e) {
                const int row = bm + wr * 64 + m * 16 + lgr * 4 + e;
                if (row < M) {
                    float v = acc[m][n][e] + bv2;
                    if (EPI == 2) v = gelu_f(v);
                    if (EPI == 3) v += resid[(size_t)row * N + col];
                    C[(size_t)row * N + col] = (OT)v;
                }
            }
        }
    }
}

// ---------------------------------------------------------------------------
// 256x256 bf16 MFMA GEMM, 8-phase-style pipeline (T3+T4).
// BK=64; LDS = 2 slots x {A: 2 row-halves, B: 2 col-halves} x 16KB = 128KB.
// 4 phases per K-tile (ks-half x n-half). Per phase: ds_read frags,
// stage half-tile(s) of a future K-tile, s_barrier, setprio(1), 16 MFMA,
// setprio(0), s_barrier. ONE counted vmcnt(2) per K-tile (phase 3) -- loads
// span the K-tile boundary, never drained to 0 in the loop.
// Stage schedule (during K-tile j, slot s=j&1):
//   p0: Ah1[s^1]<-j+1, Bh1[s^1]<-j+1   (freed end of j-1)
//   p1: Bh0[s^1]<-j+1                  (freed end of j-1)
//   p2: (none)
//   p3: Ah0[s]<-j+2 (freed after p2) ; vmcnt(2) after MFMA -> tile j+1 resident
// N%256==0, K%64==0, NK>=2. A needs ceil(M/256)*256 readable rows.
// ---------------------------------------------------------------------------
template <int EPI, typename OT>
__global__ __launch_bounds__(512, 1) void mgemm8p_k(const __hip_bfloat16* __restrict__ A,
                                                    const __hip_bfloat16* __restrict__ Wt,
                                                    const float* __restrict__ bias,
                                                    const float* __restrict__ resid,
                                                    OT* __restrict__ C,
                                                    int M, int N, int K) {
    __shared__ __align__(16) char sA[4 * 16384];   // [slot][half]
    __shared__ __align__(16) char sB[4 * 16384];
    const int t = threadIdx.x;            // 0..511
    const int lane = t & 63, w = t >> 6;  // 8 waves
    const int wr = w >> 2, wc = w & 3;    // 2 x 4 -> 128 x 64 per wave
    const int lrow = lane & 15, lgr = lane >> 4;

    // bijective XCD swizzle (T1, m204)
    const int gx = gridDim.x, nwg = gx * gridDim.y;
    const int q8 = nwg >> 3, r8 = nwg & 7;
    const int orig = blockIdx.y * gx + blockIdx.x;
    const int xcd = orig & 7, idx8 = orig >> 3;
    const int swz = (xcd < r8 ? xcd * (q8 + 1) : r8 * (q8 + 1) + (xcd - r8) * q8) + idx8;
    const int bm = (swz / gx) * 256;
    const int bn = (swz % gx) * 256;

    // staging source pointers: half-tile = 128 rows x 64 K; q = t + i*512,
    // r = q>>3 (0..127), c = q&7, swizzled chunk gc = c ^ (r&7)
    const int r0 = t >> 3,          c0 = t & 7,          gc0 = c0 ^ (r0 & 7);
    const int r1 = (t + 512) >> 3,  c1 = t & 7,          gc1 = c1 ^ (r1 & 7);
    const __hip_bfloat16* aS0 = A  + (size_t)(bm + r0) * K + gc0 * 8;
    const __hip_bfloat16* aS1 = A  + (size_t)(bm + r1) * K + gc1 * 8;
    const __hip_bfloat16* bS0 = Wt + (size_t)(bn + r0) * K + gc0 * 8;
    const __hip_bfloat16* bS1 = Wt + (size_t)(bn + r1) * K + gc1 * 8;
    const size_t hstep = (size_t)128 * K;

#define STAGE_A(h, sl, jj) do { \
    GLOAD16(aS0 + (size_t)(h) * hstep + (jj) * 64, sA + ((sl) * 2 + (h)) * 16384 + t * 16); \
    GLOAD16(aS1 + (size_t)(h) * hstep + (jj) * 64, sA + ((sl) * 2 + (h)) * 16384 + (t + 512) * 16); \
} while (0)
#define STAGE_B(h, sl, jj) do { \
    GLOAD16(bS0 + (size_t)(h) * hstep + (jj) * 64, sB + ((sl) * 2 + (h)) * 16384 + t * 16); \
    GLOAD16(bS1 + (size_t)(h) * hstep + (jj) * 64, sB + ((sl) * 2 + (h)) * 16384 + (t + 512) * 16); \
} while (0)

    // fragment read offsets (local to a 128x64 half-buffer)
    int aoff[8][2], boff[4][2];
    #pragma unroll
    for (int m = 0; m < 8; ++m) {
        int lr = m * 16 + lrow;                 // local row in wave's A-half (wr)
        #pragma unroll
        for (int ks = 0; ks < 2; ++ks)
            aoff[m][ks] = lr * 128 + (((ks * 4 + lgr) ^ (lr & 7)) << 4);
    }
    #pragma unroll
    for (int n = 0; n < 4; ++n) {
        int lc = (wc & 1) * 64 + n * 16 + lrow; // local col in wave's B-half (wc>>1)
        #pragma unroll
        for (int ks = 0; ks < 2; ++ks)
            boff[n][ks] = lc * 128 + (((ks * 4 + lgr) ^ (lc & 7)) << 4);
    }

    fx4 acc[8][4];
    #pragma unroll
    for (int m = 0; m < 8; ++m)
        #pragma unroll
        for (int n = 0; n < 4; ++n)
            #pragma unroll
            for (int e = 0; e < 4; ++e) acc[m][n][e] = 0.f;

    const int NK = K >> 6;

    // ---- prologue: tile 0 (all 4 halves) + Ah0 of tile 1 ----
    STAGE_A(0, 0, 0); STAGE_A(1, 0, 0);
    STAGE_B(0, 0, 0); STAGE_B(1, 0, 0);
    STAGE_A(0, 1, 1);
    asm volatile("s_waitcnt vmcnt(2)" ::: "memory");   // tile 0 resident
    __builtin_amdgcn_sched_barrier(0);
    __builtin_amdgcn_s_barrier();

    for (int j = 0; j < NK; ++j) {
        const int s = j & 1;
        const int jn  = (j + 1 < NK) ? j + 1 : NK - 1;
        const int jn2 = (j + 2 < NK) ? j + 2 : NK - 1;
        const char* myA = sA + (s * 2 + wr) * 16384;
        const char* myB = sB + (s * 2 + (wc >> 1)) * 16384;
        bfx8 av[8], b0, b1;

        // ---- phase 0: ks=0, n-frags 0,1 ----
        #pragma unroll
        for (int m = 0; m < 8; ++m) av[m] = *(const bfx8*)(myA + aoff[m][0]);
        b0 = *(const bfx8*)(myB + boff[0][0]);
        b1 = *(const bfx8*)(myB + boff[1][0]);
        STAGE_A(1, s ^ 1, jn);
        STAGE_B(1, s ^ 1, jn);
        __builtin_amdgcn_s_barrier();
        __builtin_amdgcn_s_setprio(1);
        #pragma unroll
        for (int m = 0; m < 8; ++m) {
            acc[m][0] = __builtin_amdgcn_mfma_f32_16x16x32_bf16(av[m], b0, acc[m][0], 0, 0, 0);
            acc[m][1] = __builtin_amdgcn_mfma_f32_16x16x32_bf16(av[m], b1, acc[m][1], 0, 0, 0);
        }
        __builtin_amdgcn_s_setprio(0);
        __builtin_amdgcn_s_barrier();

        // ---- phase 1: ks=0, n-frags 2,3 ----
        b0 = *(const bfx8*)(myB + boff[2][0]);
        b1 = *(const bfx8*)(myB + boff[3][0]);
        STAGE_B(0, s ^ 1, jn);
        __builtin_amdgcn_s_barrier();
        __builtin_amdgcn_s_setprio(1);
        #pragma unroll
        for (int m = 0; m < 8; ++m) {
            acc[m][2] = __builtin_amdgcn_mfma_f32_16x16x32_bf16(av[m], b0, acc[m][2], 0, 0, 0);
            acc[m][3] = __builtin_amdgcn_mfma_f32_16x16x32_bf16(av[m], b1, acc[m][3], 0, 0, 0);
        }
        __builtin_amdgcn_s_setprio(0);
        __builtin_amdgcn_s_barrier();

        // ---- phase 2: ks=1, n-frags 0,1 ----
        #pragma unroll
        for (int m = 0; m < 8; ++m) av[m] = *(const bfx8*)(myA + aoff[m][1]);
        b0 = *(const bfx8*)(myB + boff[0][1]);
        b1 = *(const bfx8*)(myB + boff[1][1]);
        __builtin_amdgcn_s_barrier();
        __builtin_amdgcn_s_setprio(1);
        #pragma unroll
        for (int m = 0; m < 8; ++m) {
            acc[m][0] = __builtin_amdgcn_mfma_f32_16x16x32_bf16(av[m], b0, acc[m][0], 0, 0, 0);
            acc[m][1] = __builtin_amdgcn_mfma_f32_16x16x32_bf16(av[m], b1, acc[m][1], 0, 0, 0);
        }
        __builtin_amdgcn_s_setprio(0);
        __builtin_amdgcn_s_barrier();

        // ---- phase 3: ks=1, n-frags 2,3 ----
        b0 = *(const bfx8*)(myB + boff[2][1]);
        b1 = *(const bfx8*)(myB + boff[3][1]);
        STAGE_A(0, s, jn2);     // Ah0[s] freed after phase 2
        __builtin_amdgcn_s_barrier();
        __builtin_amdgcn_s_setprio(1);
        #pragma unroll
        for (int m = 0; m < 8; ++m) {
            acc[m][2] = __builtin_amdgcn_mfma_f32_16x16x32_bf16(av[m], b0, acc[m][2], 0, 0, 0);
            acc[m][3] = __builtin_amdgcn_mfma_f32_16x16x32_bf16(av[m], b1, acc[m][3], 0, 0, 0);
        }
        __builtin_amdgcn_s_setprio(0);
        asm volatile("s_waitcnt vmcnt(2)" ::: "memory");   // tile j+1 fully resident
        __builtin_amdgcn_sched_barrier(0);
        __builtin_amdgcn_s_barrier();
    }
    asm volatile("s_waitcnt vmcnt(0)" ::: "memory");
#undef STAGE_A
#undef STAGE_B

    // ---- epilogue ----
    #pragma unroll
    for (int m = 0; m < 8; ++m) {
        #pragma unroll
        for (int n = 0; n < 4; ++n) {
            const int col = bn + wc * 64 + n * 16 + lrow;
            float bv2 = (EPI >= 1) ? bias[col] : 0.f;
            #pragma unroll
            for (int e = 0; e < 4; ++e) {
                const int row = bm + wr * 128 + m * 16 + lgr * 4 + e;
                if (row < M) {
                    float v = acc[m][n][e] + bv2;
                    if (EPI == 2) v = gelu_f(v);
                    if (EPI == 3) v += resid[(size_t)row * N + col];
                    C[(size_t)row * N + col] = (OT)v;
                }
            }
        }
    }
}

// ---------------------------------------------------------------------------
// MFMA fused attention on fused QKV buffer (row stride 2304).
// ---------------------------------------------------------------------------
__global__ __launch_bounds__(256) void attn_k(const __hip_bfloat16* __restrict__ QKV,
                                              __hip_bfloat16* __restrict__ O) {
    __shared__ __align__(16) char Ks[224 * 128];   // 28672
    __shared__ __align__(16) char VTs[64 * 464];   // 29696
    __shared__ __align__(16) char Ps[4][7424];     // 4 x (16 rows x 464B)

    const int h = blockIdx.x;
    const int b = blockIdx.y;
    const int t = threadIdx.x;
    const int lane = t & 63, w = t >> 6;
    const int rho = lane & 15, g = lane >> 4;
    const size_t base = (size_t)b * NTOK * 2304;
    const int qoff = h * 64, koff = 768 + h * 64, voff = 1536 + h * 64;
    const size_t obase = ((size_t)b * NTOK) * 768 + h * 64;

    #pragma unroll
    for (int i = 0; i < 7; ++i) {
        int q = t + i * 256;            // 0..1791
        int j = q >> 3, c = q & 7;
        int gc = c ^ (j & 7);
        GLOAD16(QKV + base + (size_t)j * 2304 + koff + gc * 8, Ks + q * 16);
    }
    #pragma unroll
    for (int i = 0; i < 7; ++i) {
        int q = t + i * 256;
        int tok = q >> 3, c = q & 7;
        bfx8 vv = {0, 0, 0, 0, 0, 0, 0, 0};
        if (tok < NTOK) vv = *(const bfx8*)(QKV + base + (size_t)tok * 2304 + voff + c * 8);
        #pragma unroll
        for (int u = 0; u < 8; ++u)
            *(unsigned short*)(VTs + (c * 8 + u) * 464 + tok * 2) = (unsigned short)vv[u];
    }
    __syncthreads();

    char* Pw = Ps[w];

    for (int qt = w; qt < 13; qt += 4) {
        const int q0 = qt * 16;
        fx4 s[13];
        #pragma unroll
        for (int nt = 0; nt < 13; ++nt)
            #pragma unroll
            for (int e = 0; e < 4; ++e) s[nt][e] = 0.f;
        #pragma unroll
        for (int ks = 0; ks < 2; ++ks) {
            bfx8 av = *(const bfx8*)(QKV + base + (size_t)(q0 + rho) * 2304 + qoff + ks * 32 + g * 8);
            #pragma unroll
            for (int nt = 0; nt < 13; ++nt) {
                int r = nt * 16 + rho;
                bfx8 bv = *(const bfx8*)(Ks + r * 128 + (((ks * 4 + g) ^ (r & 7)) << 4));
                s[nt] = __builtin_amdgcn_mfma_f32_16x16x32_bf16(av, bv, s[nt], 0, 0, 0);
            }
        }
        float mx[4] = {-1e30f, -1e30f, -1e30f, -1e30f};
        #pragma unroll
        for (int nt = 0; nt < 13; ++nt) {
            #pragma unroll
            for (int e = 0; e < 4; ++e) {
                float v = s[nt][e] * 0.125f;
                if (nt == 12 && rho >= 5) v = -1e30f;
                s[nt][e] = v;
                mx[e] = fmaxf(mx[e], v);
            }
        }
        #pragma unroll
        for (int off = 1; off < 16; off <<= 1)
            #pragma unroll
            for (int e = 0; e < 4; ++e) mx[e] = fmaxf(mx[e], __shfl_xor(mx[e], off));
        float sm[4] = {0.f, 0.f, 0.f, 0.f};
        #pragma unroll
        for (int nt = 0; nt < 13; ++nt)
            #pragma unroll
            for (int e = 0; e < 4; ++e) {
                float p = __expf(s[nt][e] - mx[e]);
                s[nt][e] = p;
                sm[e] += p;
            }
        #pragma unroll
        for (int off = 1; off < 16; off <<= 1)
            #pragma unroll
            for (int e = 0; e < 4; ++e) sm[e] += __shfl_xor(sm[e], off);
        float inv[4];
        #pragma unroll
        for (int e = 0; e < 4; ++e) inv[e] = 1.0f / sm[e];

        #pragma unroll
        for (int nt = 0; nt < 13; ++nt)
            #pragma unroll
            for (int e = 0; e < 4; ++e) {
                int row = g * 4 + e;
                int col = nt * 16 + rho;
                *(__hip_bfloat16*)(Pw + row * 464 + col * 2) =
                    (__hip_bfloat16)(s[nt][e] * inv[e]);
            }
        #pragma unroll
        for (int e = 0; e < 4; ++e)
            *(__hip_bfloat16*)(Pw + (g * 4 + e) * 464 + (208 + rho) * 2) = (__hip_bfloat16)0.0f;

        __builtin_amdgcn_sched_barrier(0);
        asm volatile("s_waitcnt lgkmcnt(0)" ::: "memory");
        __builtin_amdgcn_sched_barrier(0);

        #pragma unroll
        for (int dt = 0; dt < 4; ++dt) {
            fx4 o;
            #pragma unroll
            for (int e = 0; e < 4; ++e) o[e] = 0.f;
            #pragma unroll
            for (int ks = 0; ks < 7; ++ks) {
                bfx8 pa = *(const bfx8*)(Pw + rho * 464 + (ks * 4 + g) * 16);
                bfx8 bv = *(const bfx8*)(VTs + (dt * 16 + rho) * 464 + (ks * 4 + g) * 16);
                o = __builtin_amdgcn_mfma_f32_16x16x32_bf16(pa, bv, o, 0, 0, 0);
            }
            #pragma unroll
            for (int e = 0; e < 4; ++e) {
                int qrow = q0 + g * 4 + e;
                if (qrow < NTOK)
                    O[obase + (size_t)qrow * 768 + dt * 16 + rho] = (__hip_bfloat16)o[e];
            }
        }
    }
}

// ---------------------------------------------------------------------------
// Head softmax: out[b,:] = softmax(logits[b,:1000] + b_head)
// ---------------------------------------------------------------------------
__global__ __launch_bounds__(256) void shead_k(const float* __restrict__ logits,
                                               const float* __restrict__ bh,
                                               float* __restrict__ out) {
    const int b = blockIdx.x;
    const int t = threadIdx.x;
    __shared__ float lg[1000];
    __shared__ float red[4];

    for (int c = t; c < 1000; c += 256) lg[c] = logits[(size_t)b * 1024 + c] + bh[c];
    __syncthreads();

    float m = -1e30f;
    for (int c = t; c < 1000; c += 256) m = fmaxf(m, lg[c]);
    #pragma unroll
    for (int off = 32; off; off >>= 1) m = fmaxf(m, __shfl_xor(m, off));
    if ((t & 63) == 0) red[t >> 6] = m;
    __syncthreads();
    m = fmaxf(fmaxf(red[0], red[1]), fmaxf(red[2], red[3]));
    __syncthreads();

    float sum = 0.f;
    for (int c = t; c < 1000; c += 256) sum += __expf(lg[c] - m);
    #pragma unroll
    for (int off = 32; off; off >>= 1) sum += __shfl_xor(sum, off);
    if ((t & 63) == 0) red[t >> 6] = sum;
    __syncthreads();
    sum = red[0] + red[1] + red[2] + red[3];
    const float invs = 1.0f / sum;
    for (int c = t; c < 1000; c += 256) out[(size_t)b * 1000 + c] = __expf(lg[c] - m) * invs;
}

// ---------------------------------------------------------------------------
// Driver
// ---------------------------------------------------------------------------
extern "C" void kernel_launch(void* const* d_in, const int* in_sizes, int n_in,
                              void* d_out, int out_size, void* d_ws, size_t ws_size,
                              hipStream_t stream) {
    const float* x        = (const float*)d_in[0];
    const float* ln_p_g   = (const float*)d_in[1];
    const float* ln_p_b   = (const float*)d_in[2];
    const float* W_patch  = (const float*)d_in[3];
    const float* b_patch  = (const float*)d_in[4];
    const float* ln_e_g   = (const float*)d_in[5];
    const float* ln_e_b   = (const float*)d_in[6];
    const float* pos_emb  = (const float*)d_in[7];
    const float* cls_tok  = (const float*)d_in[8];
    const float* ln_a_g   = (const float*)d_in[9];
    const float* ln_a_b   = (const float*)d_in[10];
    const float* Wq       = (const float*)d_in[11];
    const float* Wk       = (const float*)d_in[12];
    const float* Wv       = (const float*)d_in[13];
    const float* Wo       = (const float*)d_in[14];
    const float* bo       = (const float*)d_in[15];
    const float* ln_f_g   = (const float*)d_in[16];
    const float* ln_f_b   = (const float*)d_in[17];
    const float* W1       = (const float*)d_in[18];
    const float* b1       = (const float*)d_in[19];
    const float* W2       = (const float*)d_in[20];
    const float* b2       = (const float*)d_in[21];
    const float* ln_out_g = (const float*)d_in[22];
    const float* ln_out_b = (const float*)d_in[23];
    const float* W_head   = (const float*)d_in[24];
    const float* b_head   = (const float*)d_in[25];

    typedef __hip_bfloat16 bf;
    const int M  = 12608;               // 64*197
    const int MP = 12800;               // padded to 50*256
    char* p = (char*)d_ws;

    float* Z   = (float*)p;            p += (size_t)MP * 768 * 4;      // fp32 residual
    bf* XA     = (bf*)p;               p += (size_t)MP * 768 * 2;      // LN out (bf16)
    bf* QKV    = (bf*)p;               p += (size_t)MP * 2304 * 2;     // fused q,k,v
    bf* OB     = (bf*)p;               p += (size_t)MP * 768 * 2;
    char* FFHc = p;                    p += (size_t)MP * 3072 * 2;     // bf16 GELU buf
    bf* FFH    = (bf*)FFHc;
    float* PE  = (float*)FFHc;                                          // alias: patch-embed fp32
    float* E2  = (float*)(FFHc + (size_t)MP * 768 * 4);                 // alias: ln_e out fp32
    bf* WQKVT  = (bf*)p;               p += (size_t)12 * 2304 * 768 * 2;
    bf* WoT    = (bf*)p;               p += (size_t)12 * 768 * 768 * 2;
    bf* W1T    = (bf*)p;               p += (size_t)12 * 3072 * 768 * 2;
    bf* W2T    = (bf*)p;               p += (size_t)12 * 768 * 3072 * 2;
    bf* WpT    = (bf*)p;               p += (size_t)768 * 768 * 2;
    bf* WhT    = (bf*)p;               p += (size_t)1024 * 768 * 2;
    bf* CLS    = (bf*)p;               p += (size_t)128 * 768 * 2;
    float* LOG = (float*)p;            p += (size_t)64 * 1024 * 4;

    const size_t QKVS = (size_t)2304 * 768;

    // weight convert + transpose (every launch)
    wconv_k<<<dim3(12, 12, 12), 256, 0, stream>>>(Wq, WQKVT,             768, 768,  QKVS);
    wconv_k<<<dim3(12, 12, 12), 256, 0, stream>>>(Wk, WQKVT + 768 * 768, 768, 768,  QKVS);
    wconv_k<<<dim3(12, 12, 12), 256, 0, stream>>>(Wv, WQKVT + 1536 * 768,768, 768,  QKVS);
    wconv_k<<<dim3(12, 12, 12), 256, 0, stream>>>(Wo, WoT,  768, 768,  (size_t)768 * 768);
    wconv_k<<<dim3(48, 12, 12), 256, 0, stream>>>(W1, W1T,  768, 3072, (size_t)3072 * 768);
    wconv_k<<<dim3(12, 48, 12), 256, 0, stream>>>(W2, W2T,  3072, 768, (size_t)768 * 3072);
    wconv_k<<<dim3(12, 12, 1),  256, 0, stream>>>(W_patch, WpT, 768, 768, 0);
    whT_k  <<<dim3(16, 12),     256, 0, stream>>>(W_head, WhT);

    // patch embed pipeline
    patch_ln_k<<<12544, 256, 0, stream>>>(x, XA, ln_p_g, ln_p_b);
    mgemm_k<1, float><<<dim3(6, 98), 256, 0, stream>>>(XA, WpT, b_patch, nullptr, PE, 12544, 768, 768);
    ln_k<float><<<12544, 256, 0, stream>>>(PE, E2, ln_e_g, ln_e_b);
    build_z_k<<<37824, 256, 0, stream>>>(E2, cls_tok, pos_emb, Z);

    for (int i = 0; i < 12; ++i) {
        bf* WQKVT_i = WQKVT + (size_t)i * QKVS;
        bf* WoT_i   = WoT + (size_t)i * 768 * 768;
        bf* W1T_i   = W1T + (size_t)i * 3072 * 768;
        bf* W2T_i   = W2T + (size_t)i * 768 * 3072;

        ln_k<bf><<<M, 256, 0, stream>>>(Z, XA, ln_a_g + (size_t)i * 768, ln_a_b + (size_t)i * 768);
        mgemm8p_k<0, bf><<<dim3(9, 50), 512, 0, stream>>>(XA, WQKVT_i, nullptr, nullptr, QKV, M, 2304, 768);
        attn_k<<<dim3(12, 64), 256, 0, stream>>>(QKV, OB);
        mgemm_k<3, float><<<dim3(6, 99), 256, 0, stream>>>(OB, WoT_i, bo + (size_t)i * 768, Z, Z, M, 768, 768);
        ln_k<bf><<<M, 256, 0, stream>>>(Z, XA, ln_f_g + (size_t)i * 768, ln_f_b + (size_t)i * 768);
        mgemm8p_k<2, bf><<<dim3(12, 50), 512, 0, stream>>>(XA, W1T_i, b1 + (size_t)i * 3072, nullptr, FFH, M, 3072, 768);
        mgemm_k<3, float><<<dim3(6, 99), 256, 0, stream>>>(FFH, W2T_i, b2 + (size_t)i * 768, Z, Z, M, 768, 3072);
    }

    // head: LN(CLS rows) -> logits GEMM (128^2 kernel) -> softmax
    ln_cls_k<<<128, 256, 0, stream>>>(Z, CLS, ln_out_g, ln_out_b);
    mgemm_k<0, float><<<dim3(8, 1), 256, 0, stream>>>(CLS, WhT, nullptr, nullptr, LOG, 64, 1024, 768);
    shead_k<<<64, 256, 0, stream>>>(LOG, b_head, (float*)d_out);
}